// Round 6
// baseline (1542.211 us; speedup 1.0000x reference)
//
#include <hip/hip_runtime.h>
#include <math.h>

// Problem constants
constexpr int BB  = 64;    // batch
constexpr int CIc = 3;     // image channels
constexpr int HIc = 96, WIc = 96;
constexpr int Gc  = 8, HGc = 16, WGc = 16;
constexpr int HIDc = 18432;      // 128*12*12
constexpr int HIDLINc = 512;

// ---------------------------------------------------------------------------
// conv96_v5: 3x3 conv pad=1 on 96x96, COUT=32, all oc in one block.
// Block 256 = 32 cols x 8 row-groups; each thread: 2 rows x 32 oc (64 acc).
// __launch_bounds__(256,3) gives the register allocator ~160 arch VGPRs so
// the 64 accumulators stay in VGPRs (v4's default heuristic pushed them to
// AGPRs -> accvgpr shuffles ~2.6x VALU bloat; VGPR_Count was 52).
// Register double-buffer: chunk k+1's global loads issue right after the LDS
// write of chunk k, so vmcnt waits land after a full compute phase.
// Weights via wave-uniform global addresses -> scalar loads (SGPR operand).
// ---------------------------------------------------------------------------
template<int CIN, int CBLK>
__global__ __launch_bounds__(256, 3)
void conv96_v5(const float* __restrict__ in, const float* __restrict__ wgt,
               const float* __restrict__ bias, float* __restrict__ out)
{
    constexpr int TOT = CBLK * 18 * 34;
    constexpr int NPF = (TOT + 255) / 256;

    const int tile = blockIdx.x;
    const int txi = tile % 3, tyi = tile / 3;
    const int ox = txi * 32, oy = tyi * 16;
    const int b = blockIdx.y;
    const int tid = threadIdx.x;
    const int px = tid & 31;          // col 0..31
    const int py = tid >> 5;          // 0..7 -> rows 2py, 2py+1

    __shared__ float s_in[CBLK][18][34];

    float acc0[32], acc1[32];
#pragma unroll
    for (int oc = 0; oc < 32; ++oc) { acc0[oc] = 0.0f; acc1[oc] = 0.0f; }

    // fetch one staged element of chunk cb (idx in [0, TOT))
    auto fetch = [&](int cb, int idx) -> float {
        int ci  = idx / (18 * 34);
        int rem = idx - ci * (18 * 34);
        int r = rem / 34;
        int c = rem - r * 34;
        int gy = oy + r - 1, gx = ox + c - 1;
        float v = 0.0f;
        if (gy >= 0 && gy < 96 && gx >= 0 && gx < 96)
            v = in[((size_t)(b * CIN + cb + ci) * 96 + gy) * 96 + gx];
        return v;
    };

    float pf[NPF];
    // prologue: load chunk 0 into regs
#pragma unroll
    for (int i = 0; i < NPF; ++i) {
        int idx = tid + i * 256;
        pf[i] = (idx < TOT) ? fetch(0, idx) : 0.0f;
    }

    for (int cb = 0; cb < CIN; cb += CBLK) {
        __syncthreads();               // previous compute done reading s_in
#pragma unroll
        for (int i = 0; i < NPF; ++i) {
            int idx = tid + i * 256;
            if (idx < TOT) ((float*)s_in)[idx] = pf[i];
        }
        __syncthreads();

        // issue next chunk's loads now; latency hides under compute below
        if (cb + CBLK < CIN) {
#pragma unroll
            for (int i = 0; i < NPF; ++i) {
                int idx = tid + i * 256;
                pf[i] = (idx < TOT) ? fetch(cb + CBLK, idx) : 0.0f;
            }
        }

#pragma unroll
        for (int ci = 0; ci < CBLK; ++ci) {
            float v[4][3];
#pragma unroll
            for (int r = 0; r < 4; ++r)
#pragma unroll
                for (int c = 0; c < 3; ++c)
                    v[r][c] = s_in[ci][2 * py + r][px + c];

#pragma unroll
            for (int oc = 0; oc < 32; ++oc) {
                const float* w9 = wgt + ((size_t)oc * CIN + (cb + ci)) * 9;
                float a0 = acc0[oc], a1 = acc1[oc];
#pragma unroll
                for (int dy = 0; dy < 3; ++dy)
#pragma unroll
                    for (int dx = 0; dx < 3; ++dx) {
                        float wv = w9[dy * 3 + dx];
                        a0 = fmaf(v[dy][dx],     wv, a0);
                        a1 = fmaf(v[dy + 1][dx], wv, a1);
                    }
                acc0[oc] = a0; acc1[oc] = a1;
            }
        }
    }

#pragma unroll
    for (int oc = 0; oc < 32; ++oc) {
        float bv = bias[oc];
        size_t base = ((size_t)(b * 32 + oc) * 96 + oy + 2 * py) * 96 + ox + px;
        out[base]      = fmaxf(acc0[oc] + bv, 0.0f);
        out[base + 96] = fmaxf(acc1[oc] + bv, 0.0f);
    }
}

// ---------------------------------------------------------------------------
// Split-K direct 3x3 conv (round-2 form): partials [KS][B][COUT][H][W].
// ---------------------------------------------------------------------------
template<int CIN, int COUT, int H, int W, int TH, int TW, int KS>
__global__ __launch_bounds__(TH * TW)
void conv3x3_split(const float* __restrict__ in, const float* __restrict__ wgt,
                   float* __restrict__ partial)
{
    constexpr int CBLK = CIN / KS;
    constexpr int NTX = W / TW;
    const int tx = blockIdx.x % NTX, ty = blockIdx.x / NTX;
    const int b  = blockIdx.y;
    const int chunk = blockIdx.z / KS;
    const int ks    = blockIdx.z % KS;
    const int coutBase = chunk * 32;
    const int cinBase  = ks * CBLK;
    const int tid = threadIdx.x;
    const int px = tid % TW, py = tid / TW;
    const int ox = tx * TW, oy = ty * TH;

    __shared__ float s_in[CBLK][TH + 2][TW + 2];

    constexpr int TOT = CBLK * (TH + 2) * (TW + 2);
    for (int idx = tid; idx < TOT; idx += TH * TW) {
        int ci  = idx / ((TH + 2) * (TW + 2));
        int rem = idx % ((TH + 2) * (TW + 2));
        int yy = rem / (TW + 2), xx = rem % (TW + 2);
        int gy = oy + yy - 1, gx = ox + xx - 1;
        float v = 0.0f;
        if (gy >= 0 && gy < H && gx >= 0 && gx < W)
            v = in[((size_t)(b * CIN + cinBase + ci) * H + gy) * W + gx];
        s_in[ci][yy][xx] = v;
    }
    __syncthreads();

    float acc[32];
#pragma unroll
    for (int oc = 0; oc < 32; ++oc) acc[oc] = 0.0f;

    for (int ci = 0; ci < CBLK; ++ci) {
        float v[9];
#pragma unroll
        for (int dy = 0; dy < 3; ++dy)
#pragma unroll
            for (int dx = 0; dx < 3; ++dx)
                v[dy * 3 + dx] = s_in[ci][py + dy][px + dx];

#pragma unroll
        for (int oc = 0; oc < 32; ++oc) {
            const float* w9 =
                wgt + ((size_t)(coutBase + oc) * CIN + (cinBase + ci)) * 9;
#pragma unroll
            for (int k = 0; k < 9; ++k)
                acc[oc] = fmaf(v[k], w9[k], acc[oc]);
        }
    }

#pragma unroll
    for (int oc = 0; oc < 32; ++oc) {
        partial[(((size_t)ks * BB + b) * COUT + coutBase + oc) * (H * W) +
                (oy + py) * W + ox + px] = acc[oc];
    }
}

// Sum split-K partials + bias + ReLU
template<int C, int H, int W, int KS>
__global__ void conv_reduce(const float* __restrict__ partial,
                            const float* __restrict__ bias,
                            float* __restrict__ out)
{
    constexpr int TOTAL = BB * C * H * W;
    int idx = blockIdx.x * blockDim.x + threadIdx.x;
    if (idx >= TOTAL) return;
    int c = (idx / (H * W)) % C;
    float s = bias[c];
#pragma unroll
    for (int k = 0; k < KS; ++k)
        s += partial[(size_t)k * TOTAL + idx];
    out[idx] = fmaxf(s, 0.0f);
}

// ---------------------------------------------------------------------------
// Max pool KxK, stride K
// ---------------------------------------------------------------------------
template<int C, int H, int W, int K>
__global__ void maxpool_k(const float* __restrict__ in, float* __restrict__ out)
{
    constexpr int HO = H / K, WO = W / K;
    int idx = blockIdx.x * blockDim.x + threadIdx.x;
    constexpr int TOTAL = BB * C * HO * WO;
    if (idx >= TOTAL) return;
    int wo = idx % WO; int t = idx / WO;
    int ho = t % HO; t /= HO;
    int c = t % C; int b = t / C;
    const float* p = in + ((size_t)(b * C + c) * H + ho * K) * W + wo * K;
    float m = -INFINITY;
#pragma unroll
    for (int i = 0; i < K; ++i)
#pragma unroll
        for (int j = 0; j < K; ++j)
            m = fmaxf(m, p[i * W + j]);
    out[idx] = m;
}

// ---------------------------------------------------------------------------
// lin1: (64, 18432) @ (18432, 512), split-K partials.
// ---------------------------------------------------------------------------
constexpr int KSPLIT = 64;              // 18432 / 64 = 288 per split
__global__ __launch_bounds__(256)
void lin1_partial(const float* __restrict__ x, const float* __restrict__ w,
                  float* __restrict__ partial)
{
    const int j  = threadIdx.x % 64;
    const int bg = threadIdx.x / 64;          // 0..3
    const int jBase = blockIdx.x * 64;        // 8 tiles of 64
    const int k  = blockIdx.y;                // 0..63
    const int i0 = k * 288;

    __shared__ float s_x[32][64];

    float acc[16];
#pragma unroll
    for (int u = 0; u < 16; ++u) acc[u] = 0.0f;

    for (int ib = 0; ib < 288; ib += 32) {
        __syncthreads();
        {
            int lb = threadIdx.x / 4;           // b 0..63
            int lo = (threadIdx.x % 4) * 8;     // ii 0,8,16,24
            const float* src = x + (size_t)lb * HIDc + i0 + ib + lo;
            float4 a0 = *(const float4*)(src);
            float4 a1 = *(const float4*)(src + 4);
            float tmp[8] = {a0.x, a0.y, a0.z, a0.w, a1.x, a1.y, a1.z, a1.w};
#pragma unroll
            for (int r = 0; r < 8; ++r) s_x[lo + r][lb] = tmp[r];
        }
        __syncthreads();

        for (int ii = 0; ii < 32; ++ii) {
            float wv = w[(size_t)(i0 + ib + ii) * HIDLINc + jBase + j];
            const float4* xp = (const float4*)&s_x[ii][bg * 16];
            float4 x0 = xp[0], x1 = xp[1], x2 = xp[2], x3 = xp[3];
            acc[0]  = fmaf(x0.x, wv, acc[0]);
            acc[1]  = fmaf(x0.y, wv, acc[1]);
            acc[2]  = fmaf(x0.z, wv, acc[2]);
            acc[3]  = fmaf(x0.w, wv, acc[3]);
            acc[4]  = fmaf(x1.x, wv, acc[4]);
            acc[5]  = fmaf(x1.y, wv, acc[5]);
            acc[6]  = fmaf(x1.z, wv, acc[6]);
            acc[7]  = fmaf(x1.w, wv, acc[7]);
            acc[8]  = fmaf(x2.x, wv, acc[8]);
            acc[9]  = fmaf(x2.y, wv, acc[9]);
            acc[10] = fmaf(x2.z, wv, acc[10]);
            acc[11] = fmaf(x2.w, wv, acc[11]);
            acc[12] = fmaf(x3.x, wv, acc[12]);
            acc[13] = fmaf(x3.y, wv, acc[13]);
            acc[14] = fmaf(x3.z, wv, acc[14]);
            acc[15] = fmaf(x3.w, wv, acc[15]);
        }
    }

#pragma unroll
    for (int u = 0; u < 16; ++u) {
        int b = bg * 16 + u;
        partial[((size_t)k * 64 + b) * HIDLINc + jBase + j] = acc[u];
    }
}

__global__ void lin1_reduce(const float* __restrict__ partial,
                            const float* __restrict__ bias,
                            float* __restrict__ x1)
{
    int idx = blockIdx.x * blockDim.x + threadIdx.x;  // 64*512
    if (idx >= 64 * HIDLINc) return;
    int j = idx % HIDLINc;
    float s = 0.0f;
    for (int k = 0; k < KSPLIT; ++k)
        s += partial[(size_t)k * 64 * HIDLINc + idx];
    x1[idx] = fmaxf(s + bias[j], 0.0f);
}

// ---------------------------------------------------------------------------
// lin2: (64,512) @ (512,512) + bias + relu
// ---------------------------------------------------------------------------
__global__ __launch_bounds__(256)
void lin2_k(const float* __restrict__ x1, const float* __restrict__ w,
            const float* __restrict__ bias, float* __restrict__ x2)
{
    const int j  = threadIdx.x % 64;
    const int bl = threadIdx.x / 64;          // 0..3
    const int jBase = blockIdx.x * 64;        // 8
    const int b = blockIdx.y * 4 + bl;        // 16 groups of 4

    __shared__ float s_x[4][HIDLINc];
    for (int idx = threadIdx.x; idx < 4 * HIDLINc; idx += 256)
        s_x[idx / HIDLINc][idx % HIDLINc] =
            x1[(size_t)(blockIdx.y * 4 + idx / HIDLINc) * HIDLINc + idx % HIDLINc];
    __syncthreads();

    float acc = 0.0f;
    for (int i = 0; i < HIDLINc; ++i)
        acc = fmaf(s_x[bl][i], w[(size_t)i * HIDLINc + jBase + j], acc);
    x2[(size_t)b * HIDLINc + jBase + j] = fmaxf(acc + bias[jBase + j], 0.0f);
}

// ---------------------------------------------------------------------------
// lin3: (64,512) @ (512,24) + bias
// ---------------------------------------------------------------------------
__global__ void lin3_k(const float* __restrict__ x2, const float* __restrict__ w,
                       const float* __restrict__ bias, float* __restrict__ prep)
{
    int idx = blockIdx.x * blockDim.x + threadIdx.x;
    if (idx >= 64 * 24) return;
    int j = idx % 24, b = idx / 24;
    float acc = bias[j];
    for (int i = 0; i < HIDLINc; ++i)
        acc = fmaf(x2[(size_t)b * HIDLINc + i], w[i * 24 + j], acc);
    prep[idx] = acc;
}

// ---------------------------------------------------------------------------
// Head: means/sigmas/sample/points.  round = half-to-even (rintf)
// ---------------------------------------------------------------------------
__global__ void head_k(const float* __restrict__ prep, const float* __restrict__ noise,
                       float* __restrict__ outMeans, float* __restrict__ outSigmas,
                       int* __restrict__ pts)
{
    int id = blockIdx.x * blockDim.x + threadIdx.x;
    if (id >= BB * Gc) return;
    float m0 = prep[id * 3 + 0];
    float m1 = prep[id * 3 + 1];
    float sraw = prep[id * 3 + 2];
    float s = sraw + 2.0f;                       // SIGMA_BOOST
    float sig = fmaxf(s, 0.0f) + log1pf(expf(-fabsf(s)));
    sig += 1e-7f;                                // EPS
    float sg = sig * 95.0f;                      // (HI-1) == (WI-1)
    outMeans[id * 2 + 0] = m0;
    outMeans[id * 2 + 1] = m1;
    outSigmas[id * 2 + 0] = sg;
    outSigmas[id * 2 + 1] = sg;
    float sa0 = m0 + sg * noise[id * 2 + 0];
    float sa1 = m1 + sg * noise[id * 2 + 1];
    float t0 = 1.0f / (1.0f + expf(-sa0));
    float t1 = 1.0f / (1.0f + expf(-sa1));
    pts[id * 2 + 0] = (int)rintf(t0 * 79.0f);    // HI-HG-1
    pts[id * 2 + 1] = (int)rintf(t1 * 79.0f);    // WI-WG-1
}

// ---------------------------------------------------------------------------
// Patch extraction: copy (3,16,16) patch per (b,g)
// ---------------------------------------------------------------------------
__global__ __launch_bounds__(256)
void patch_k(const float* __restrict__ image, const int* __restrict__ pts,
             float* __restrict__ outR)
{
    int id = blockIdx.x;                  // b*G + g
    int b = id / Gc;
    int p0 = pts[id * 2 + 0];
    int p1 = pts[id * 2 + 1];
    for (int idx = threadIdx.x; idx < CIc * HGc * WGc; idx += 256) {
        int c = idx / (HGc * WGc), rem = idx % (HGc * WGc);
        int hh = rem / WGc, ww = rem % WGc;
        outR[(size_t)id * (CIc * HGc * WGc) + idx] =
            image[((size_t)(b * CIc + c) * HIc + p0 + hh) * WIc + p1 + ww];
    }
}

// ---------------------------------------------------------------------------
extern "C" void kernel_launch(void* const* d_in, const int* in_sizes, int n_in,
                              void* d_out, int out_size, void* d_ws, size_t ws_size,
                              hipStream_t stream)
{
    const float* image = (const float*)d_in[0];
    const float* noise = (const float*)d_in[1];
    const float* w1a = (const float*)d_in[2];
    const float* b1a = (const float*)d_in[3];
    const float* w1b = (const float*)d_in[4];
    const float* b1b = (const float*)d_in[5];
    const float* w2a = (const float*)d_in[6];
    const float* b2a = (const float*)d_in[7];
    const float* w2b = (const float*)d_in[8];
    const float* b2b = (const float*)d_in[9];
    const float* w3a = (const float*)d_in[10];
    const float* b3a = (const float*)d_in[11];
    const float* w3b = (const float*)d_in[12];
    const float* b3b = (const float*)d_in[13];
    const float* wl1 = (const float*)d_in[14];
    const float* bl1 = (const float*)d_in[15];
    const float* wl2 = (const float*)d_in[16];
    const float* bl2 = (const float*)d_in[17];
    const float* wl3 = (const float*)d_in[18];
    const float* bl3 = (const float*)d_in[19];

    float* out = (float*)d_out;
    float* ws  = (float*)d_ws;

    // Workspace layout (floats): two big regions A,B of 18,874,368 floats.
    constexpr size_t BIGF = (size_t)BB * 32 * HIc * WIc;   // 18,874,368 floats
    constexpr size_t MF = 1u << 20;
    float* A  = ws;
    float* Bf = ws + BIGF;
    float* t0   = A;                 // pool1 out      (1,179,648)
    float* t1   = A + 2 * MF;        // conv2a out     (2,359,296)
    float* t2   = A + 5 * MF;        // conv2b out     (2,359,296)
    float* t3   = A + 8 * MF;        // pool2 out        (589,824)
    float* t4   = A + 9 * MF;        // conv3a out     (1,179,648)
    float* t5   = A + 11 * MF;       // conv3b out / x (1,179,648)
    float* part = A + 13 * MF;       // lin1 partials  (2,097,152)
    float* x1   = A + 16 * MF;       // 32768
    float* x2   = x1 + 64 * HIDLINc; // 32768
    float* prep = x2 + 64 * HIDLINc; // 1536
    int*   pts  = (int*)(prep + 2048);

    // conv1a: image(64,3,96,96) -> A(64,32,96,96)
    conv96_v5<3, 3><<<dim3(18, 64), 256, 0, stream>>>(image, w1a, b1a, A);
    // conv1b: A -> B (64,32,96,96)
    conv96_v5<32, 8><<<dim3(18, 64), 256, 0, stream>>>(A, w1b, b1b, Bf);
    // pool 4x4: B -> t0 (64,32,24,24)
    maxpool_k<32, 96, 96, 4>
        <<<(BB * 32 * 24 * 24 + 255) / 256, 256, 0, stream>>>(Bf, t0);

    // conv2a: t0 -> partial(B) -> t1 (64,64,24,24); KS=2
    conv3x3_split<32, 64, 24, 24, 8, 24, 2>
        <<<dim3(3, 64, 2 * 2), 192, 0, stream>>>(t0, w2a, Bf);
    conv_reduce<64, 24, 24, 2>
        <<<(BB * 64 * 576 + 255) / 256, 256, 0, stream>>>(Bf, b2a, t1);

    // conv2b: t1 -> partial(B) -> t2; KS=4
    conv3x3_split<64, 64, 24, 24, 8, 24, 4>
        <<<dim3(3, 64, 2 * 4), 192, 0, stream>>>(t1, w2b, Bf);
    conv_reduce<64, 24, 24, 4>
        <<<(BB * 64 * 576 + 255) / 256, 256, 0, stream>>>(Bf, b2b, t2);

    // pool 2x2: t2 -> t3 (64,64,12,12)
    maxpool_k<64, 24, 24, 2>
        <<<(BB * 64 * 12 * 12 + 255) / 256, 256, 0, stream>>>(t2, t3);

    // conv3a: t3 -> partial(B) -> t4 (64,128,12,12); KS=4
    conv3x3_split<64, 128, 12, 12, 12, 12, 4>
        <<<dim3(1, 64, 4 * 4), 144, 0, stream>>>(t3, w3a, Bf);
    conv_reduce<128, 12, 12, 4>
        <<<(BB * 128 * 144 + 255) / 256, 256, 0, stream>>>(Bf, b3a, t4);

    // conv3b: t4 -> partial(B) -> t5; KS=8
    conv3x3_split<128, 128, 12, 12, 12, 12, 8>
        <<<dim3(1, 64, 4 * 8), 144, 0, stream>>>(t4, w3b, Bf);
    conv_reduce<128, 12, 12, 8>
        <<<(BB * 128 * 144 + 255) / 256, 256, 0, stream>>>(Bf, b3b, t5);

    // lin1: x @ wl1 (+bl1, relu) via split-K
    lin1_partial<<<dim3(8, KSPLIT), 256, 0, stream>>>(t5, wl1, part);
    lin1_reduce<<<(64 * HIDLINc + 255) / 256, 256, 0, stream>>>(part, bl1, x1);
    // lin2
    lin2_k<<<dim3(8, 16), 256, 0, stream>>>(x1, wl2, bl2, x2);
    // lin3 -> prep (64,24)
    lin3_k<<<6, 256, 0, stream>>>(x2, wl3, bl3, prep);
    // head -> means/sigmas into out, pts into ws
    head_k<<<2, 256, 0, stream>>>(prep, noise,
                                  out + (size_t)BB * Gc * CIc * HGc * WGc,
                                  out + (size_t)BB * Gc * CIc * HGc * WGc + BB * Gc * 2,
                                  pts);
    // patch extraction -> out[0 .. 393216)
    patch_k<<<BB * Gc, 256, 0, stream>>>(image, pts, out);
}

// Round 7
// 866.979 us; speedup vs baseline: 1.7788x; 1.7788x over previous
//
#include <hip/hip_runtime.h>
#include <math.h>

// Problem constants
constexpr int BB  = 64;    // batch
constexpr int CIc = 3;     // image channels
constexpr int HIc = 96, WIc = 96;
constexpr int Gc  = 8, HGc = 16, WGc = 16;
constexpr int HIDc = 18432;      // 128*12*12
constexpr int HIDLINc = 512;

// ---------------------------------------------------------------------------
// conv96_v6: 3x3 conv pad=1 on 96x96, COUT=32.
// Occupancy-first redesign: tile 32x8, 256 thr, 1 row x 32 oc per thread
// (32 acc). Grid 36x64 = 2304 blocks = 9216 waves (machine holds 8192), so
// s_load (weight) and ds_read waits overlap across ~6 blocks/CU.
// Weights via wave-uniform global addresses -> scalar s_load + SGPR-operand
// v_fmac (proven by round-2/4 counters: VGPR 52-68, SGPR 112).
// Per ci per wave: 9 ds_read + 288 v_fmac (97% FMA density).
// ---------------------------------------------------------------------------
template<int CIN, int CBLK>
__global__ __launch_bounds__(256, 6)
void conv96_v6(const float* __restrict__ in, const float* __restrict__ wgt,
               const float* __restrict__ bias, float* __restrict__ out)
{
    const int txi = blockIdx.x % 3, tyi = blockIdx.x / 3;   // 3 x 12 tiles
    const int ox = txi * 32, oy = tyi * 8;
    const int b = blockIdx.y;
    const int tid = threadIdx.x;
    const int px = tid & 31;          // col 0..31
    const int py = tid >> 5;          // row 0..7

    __shared__ float s_in[CBLK][10][34];

    float acc[32];
#pragma unroll
    for (int oc = 0; oc < 32; ++oc) acc[oc] = 0.0f;

    for (int cb = 0; cb < CIN; cb += CBLK) {
        __syncthreads();
        constexpr int TOT = CBLK * 10 * 34;
        for (int idx = tid; idx < TOT; idx += 256) {
            int ci  = idx / 340;
            int rem = idx - ci * 340;
            int r = rem / 34;
            int c = rem - r * 34;
            int gy = oy + r - 1, gx = ox + c - 1;
            float v = 0.0f;
            if (gy >= 0 && gy < 96 && gx >= 0 && gx < 96)
                v = in[((size_t)(b * CIN + cb + ci) * 96 + gy) * 96 + gx];
            s_in[ci][r][c] = v;
        }
        __syncthreads();

        for (int ci = 0; ci < CBLK; ++ci) {
            float v[3][3];
#pragma unroll
            for (int r = 0; r < 3; ++r)
#pragma unroll
                for (int c = 0; c < 3; ++c)
                    v[r][c] = s_in[ci][py + r][px + c];

#pragma unroll
            for (int oc = 0; oc < 32; ++oc) {
                const float* w9 = wgt + ((size_t)oc * CIN + (cb + ci)) * 9;
                float a = acc[oc];
#pragma unroll
                for (int dy = 0; dy < 3; ++dy)
#pragma unroll
                    for (int dx = 0; dx < 3; ++dx)
                        a = fmaf(v[dy][dx], w9[dy * 3 + dx], a);
                acc[oc] = a;
            }
        }
    }

#pragma unroll
    for (int oc = 0; oc < 32; ++oc) {
        out[((size_t)(b * 32 + oc) * 96 + oy + py) * 96 + ox + px] =
            fmaxf(acc[oc] + bias[oc], 0.0f);
    }
}

// ---------------------------------------------------------------------------
// Split-K direct 3x3 conv (round-2 form): partials [KS][B][COUT][H][W].
// ---------------------------------------------------------------------------
template<int CIN, int COUT, int H, int W, int TH, int TW, int KS>
__global__ __launch_bounds__(TH * TW)
void conv3x3_split(const float* __restrict__ in, const float* __restrict__ wgt,
                   float* __restrict__ partial)
{
    constexpr int CBLK = CIN / KS;
    constexpr int NTX = W / TW;
    const int tx = blockIdx.x % NTX, ty = blockIdx.x / NTX;
    const int b  = blockIdx.y;
    const int chunk = blockIdx.z / KS;
    const int ks    = blockIdx.z % KS;
    const int coutBase = chunk * 32;
    const int cinBase  = ks * CBLK;
    const int tid = threadIdx.x;
    const int px = tid % TW, py = tid / TW;
    const int ox = tx * TW, oy = ty * TH;

    __shared__ float s_in[CBLK][TH + 2][TW + 2];

    constexpr int TOT = CBLK * (TH + 2) * (TW + 2);
    for (int idx = tid; idx < TOT; idx += TH * TW) {
        int ci  = idx / ((TH + 2) * (TW + 2));
        int rem = idx % ((TH + 2) * (TW + 2));
        int yy = rem / (TW + 2), xx = rem % (TW + 2);
        int gy = oy + yy - 1, gx = ox + xx - 1;
        float v = 0.0f;
        if (gy >= 0 && gy < H && gx >= 0 && gx < W)
            v = in[((size_t)(b * CIN + cinBase + ci) * H + gy) * W + gx];
        s_in[ci][yy][xx] = v;
    }
    __syncthreads();

    float acc[32];
#pragma unroll
    for (int oc = 0; oc < 32; ++oc) acc[oc] = 0.0f;

    for (int ci = 0; ci < CBLK; ++ci) {
        float v[9];
#pragma unroll
        for (int dy = 0; dy < 3; ++dy)
#pragma unroll
            for (int dx = 0; dx < 3; ++dx)
                v[dy * 3 + dx] = s_in[ci][py + dy][px + dx];

#pragma unroll
        for (int oc = 0; oc < 32; ++oc) {
            const float* w9 =
                wgt + ((size_t)(coutBase + oc) * CIN + (cinBase + ci)) * 9;
#pragma unroll
            for (int k = 0; k < 9; ++k)
                acc[oc] = fmaf(v[k], w9[k], acc[oc]);
        }
    }

#pragma unroll
    for (int oc = 0; oc < 32; ++oc) {
        partial[(((size_t)ks * BB + b) * COUT + coutBase + oc) * (H * W) +
                (oy + py) * W + ox + px] = acc[oc];
    }
}

// Sum split-K partials + bias + ReLU
template<int C, int H, int W, int KS>
__global__ void conv_reduce(const float* __restrict__ partial,
                            const float* __restrict__ bias,
                            float* __restrict__ out)
{
    constexpr int TOTAL = BB * C * H * W;
    int idx = blockIdx.x * blockDim.x + threadIdx.x;
    if (idx >= TOTAL) return;
    int c = (idx / (H * W)) % C;
    float s = bias[c];
#pragma unroll
    for (int k = 0; k < KS; ++k)
        s += partial[(size_t)k * TOTAL + idx];
    out[idx] = fmaxf(s, 0.0f);
}

// ---------------------------------------------------------------------------
// Max pool KxK, stride K
// ---------------------------------------------------------------------------
template<int C, int H, int W, int K>
__global__ void maxpool_k(const float* __restrict__ in, float* __restrict__ out)
{
    constexpr int HO = H / K, WO = W / K;
    int idx = blockIdx.x * blockDim.x + threadIdx.x;
    constexpr int TOTAL = BB * C * HO * WO;
    if (idx >= TOTAL) return;
    int wo = idx % WO; int t = idx / WO;
    int ho = t % HO; t /= HO;
    int c = t % C; int b = t / C;
    const float* p = in + ((size_t)(b * C + c) * H + ho * K) * W + wo * K;
    float m = -INFINITY;
#pragma unroll
    for (int i = 0; i < K; ++i)
#pragma unroll
        for (int j = 0; j < K; ++j)
            m = fmaxf(m, p[i * W + j]);
    out[idx] = m;
}

// ---------------------------------------------------------------------------
// lin1: (64, 18432) @ (18432, 512), split-K partials.
// ---------------------------------------------------------------------------
constexpr int KSPLIT = 64;              // 18432 / 64 = 288 per split
__global__ __launch_bounds__(256)
void lin1_partial(const float* __restrict__ x, const float* __restrict__ w,
                  float* __restrict__ partial)
{
    const int j  = threadIdx.x % 64;
    const int bg = threadIdx.x / 64;          // 0..3
    const int jBase = blockIdx.x * 64;        // 8 tiles of 64
    const int k  = blockIdx.y;                // 0..63
    const int i0 = k * 288;

    __shared__ float s_x[32][64];

    float acc[16];
#pragma unroll
    for (int u = 0; u < 16; ++u) acc[u] = 0.0f;

    for (int ib = 0; ib < 288; ib += 32) {
        __syncthreads();
        {
            int lb = threadIdx.x / 4;           // b 0..63
            int lo = (threadIdx.x % 4) * 8;     // ii 0,8,16,24
            const float* src = x + (size_t)lb * HIDc + i0 + ib + lo;
            float4 a0 = *(const float4*)(src);
            float4 a1 = *(const float4*)(src + 4);
            float tmp[8] = {a0.x, a0.y, a0.z, a0.w, a1.x, a1.y, a1.z, a1.w};
#pragma unroll
            for (int r = 0; r < 8; ++r) s_x[lo + r][lb] = tmp[r];
        }
        __syncthreads();

        for (int ii = 0; ii < 32; ++ii) {
            float wv = w[(size_t)(i0 + ib + ii) * HIDLINc + jBase + j];
            const float4* xp = (const float4*)&s_x[ii][bg * 16];
            float4 x0 = xp[0], x1 = xp[1], x2 = xp[2], x3 = xp[3];
            acc[0]  = fmaf(x0.x, wv, acc[0]);
            acc[1]  = fmaf(x0.y, wv, acc[1]);
            acc[2]  = fmaf(x0.z, wv, acc[2]);
            acc[3]  = fmaf(x0.w, wv, acc[3]);
            acc[4]  = fmaf(x1.x, wv, acc[4]);
            acc[5]  = fmaf(x1.y, wv, acc[5]);
            acc[6]  = fmaf(x1.z, wv, acc[6]);
            acc[7]  = fmaf(x1.w, wv, acc[7]);
            acc[8]  = fmaf(x2.x, wv, acc[8]);
            acc[9]  = fmaf(x2.y, wv, acc[9]);
            acc[10] = fmaf(x2.z, wv, acc[10]);
            acc[11] = fmaf(x2.w, wv, acc[11]);
            acc[12] = fmaf(x3.x, wv, acc[12]);
            acc[13] = fmaf(x3.y, wv, acc[13]);
            acc[14] = fmaf(x3.z, wv, acc[14]);
            acc[15] = fmaf(x3.w, wv, acc[15]);
        }
    }

#pragma unroll
    for (int u = 0; u < 16; ++u) {
        int b = bg * 16 + u;
        partial[((size_t)k * 64 + b) * HIDLINc + jBase + j] = acc[u];
    }
}

__global__ void lin1_reduce(const float* __restrict__ partial,
                            const float* __restrict__ bias,
                            float* __restrict__ x1)
{
    int idx = blockIdx.x * blockDim.x + threadIdx.x;  // 64*512
    if (idx >= 64 * HIDLINc) return;
    int j = idx % HIDLINc;
    float s = 0.0f;
    for (int k = 0; k < KSPLIT; ++k)
        s += partial[(size_t)k * 64 * HIDLINc + idx];
    x1[idx] = fmaxf(s + bias[j], 0.0f);
}

// ---------------------------------------------------------------------------
// lin2: (64,512) @ (512,512) + bias + relu
// ---------------------------------------------------------------------------
__global__ __launch_bounds__(256)
void lin2_k(const float* __restrict__ x1, const float* __restrict__ w,
            const float* __restrict__ bias, float* __restrict__ x2)
{
    const int j  = threadIdx.x % 64;
    const int bl = threadIdx.x / 64;          // 0..3
    const int jBase = blockIdx.x * 64;        // 8
    const int b = blockIdx.y * 4 + bl;        // 16 groups of 4

    __shared__ float s_x[4][HIDLINc];
    for (int idx = threadIdx.x; idx < 4 * HIDLINc; idx += 256)
        s_x[idx / HIDLINc][idx % HIDLINc] =
            x1[(size_t)(blockIdx.y * 4 + idx / HIDLINc) * HIDLINc + idx % HIDLINc];
    __syncthreads();

    float acc = 0.0f;
    for (int i = 0; i < HIDLINc; ++i)
        acc = fmaf(s_x[bl][i], w[(size_t)i * HIDLINc + jBase + j], acc);
    x2[(size_t)b * HIDLINc + jBase + j] = fmaxf(acc + bias[jBase + j], 0.0f);
}

// ---------------------------------------------------------------------------
// lin3: (64,512) @ (512,24) + bias
// ---------------------------------------------------------------------------
__global__ void lin3_k(const float* __restrict__ x2, const float* __restrict__ w,
                       const float* __restrict__ bias, float* __restrict__ prep)
{
    int idx = blockIdx.x * blockDim.x + threadIdx.x;
    if (idx >= 64 * 24) return;
    int j = idx % 24, b = idx / 24;
    float acc = bias[j];
    for (int i = 0; i < HIDLINc; ++i)
        acc = fmaf(x2[(size_t)b * HIDLINc + i], w[i * 24 + j], acc);
    prep[idx] = acc;
}

// ---------------------------------------------------------------------------
// Head: means/sigmas/sample/points.  round = half-to-even (rintf)
// ---------------------------------------------------------------------------
__global__ void head_k(const float* __restrict__ prep, const float* __restrict__ noise,
                       float* __restrict__ outMeans, float* __restrict__ outSigmas,
                       int* __restrict__ pts)
{
    int id = blockIdx.x * blockDim.x + threadIdx.x;
    if (id >= BB * Gc) return;
    float m0 = prep[id * 3 + 0];
    float m1 = prep[id * 3 + 1];
    float sraw = prep[id * 3 + 2];
    float s = sraw + 2.0f;                       // SIGMA_BOOST
    float sig = fmaxf(s, 0.0f) + log1pf(expf(-fabsf(s)));
    sig += 1e-7f;                                // EPS
    float sg = sig * 95.0f;                      // (HI-1) == (WI-1)
    outMeans[id * 2 + 0] = m0;
    outMeans[id * 2 + 1] = m1;
    outSigmas[id * 2 + 0] = sg;
    outSigmas[id * 2 + 1] = sg;
    float sa0 = m0 + sg * noise[id * 2 + 0];
    float sa1 = m1 + sg * noise[id * 2 + 1];
    float t0 = 1.0f / (1.0f + expf(-sa0));
    float t1 = 1.0f / (1.0f + expf(-sa1));
    pts[id * 2 + 0] = (int)rintf(t0 * 79.0f);    // HI-HG-1
    pts[id * 2 + 1] = (int)rintf(t1 * 79.0f);    // WI-WG-1
}

// ---------------------------------------------------------------------------
// Patch extraction: copy (3,16,16) patch per (b,g)
// ---------------------------------------------------------------------------
__global__ __launch_bounds__(256)
void patch_k(const float* __restrict__ image, const int* __restrict__ pts,
             float* __restrict__ outR)
{
    int id = blockIdx.x;                  // b*G + g
    int b = id / Gc;
    int p0 = pts[id * 2 + 0];
    int p1 = pts[id * 2 + 1];
    for (int idx = threadIdx.x; idx < CIc * HGc * WGc; idx += 256) {
        int c = idx / (HGc * WGc), rem = idx % (HGc * WGc);
        int hh = rem / WGc, ww = rem % WGc;
        outR[(size_t)id * (CIc * HGc * WGc) + idx] =
            image[((size_t)(b * CIc + c) * HIc + p0 + hh) * WIc + p1 + ww];
    }
}

// ---------------------------------------------------------------------------
extern "C" void kernel_launch(void* const* d_in, const int* in_sizes, int n_in,
                              void* d_out, int out_size, void* d_ws, size_t ws_size,
                              hipStream_t stream)
{
    const float* image = (const float*)d_in[0];
    const float* noise = (const float*)d_in[1];
    const float* w1a = (const float*)d_in[2];
    const float* b1a = (const float*)d_in[3];
    const float* w1b = (const float*)d_in[4];
    const float* b1b = (const float*)d_in[5];
    const float* w2a = (const float*)d_in[6];
    const float* b2a = (const float*)d_in[7];
    const float* w2b = (const float*)d_in[8];
    const float* b2b = (const float*)d_in[9];
    const float* w3a = (const float*)d_in[10];
    const float* b3a = (const float*)d_in[11];
    const float* w3b = (const float*)d_in[12];
    const float* b3b = (const float*)d_in[13];
    const float* wl1 = (const float*)d_in[14];
    const float* bl1 = (const float*)d_in[15];
    const float* wl2 = (const float*)d_in[16];
    const float* bl2 = (const float*)d_in[17];
    const float* wl3 = (const float*)d_in[18];
    const float* bl3 = (const float*)d_in[19];

    float* out = (float*)d_out;
    float* ws  = (float*)d_ws;

    // Workspace layout (floats): two big regions A,B of 18,874,368 floats.
    constexpr size_t BIGF = (size_t)BB * 32 * HIc * WIc;   // 18,874,368 floats
    constexpr size_t MF = 1u << 20;
    float* A  = ws;
    float* Bf = ws + BIGF;
    float* t0   = A;                 // pool1 out      (1,179,648)
    float* t1   = A + 2 * MF;        // conv2a out     (2,359,296)
    float* t2   = A + 5 * MF;        // conv2b out     (2,359,296)
    float* t3   = A + 8 * MF;        // pool2 out        (589,824)
    float* t4   = A + 9 * MF;        // conv3a out     (1,179,648)
    float* t5   = A + 11 * MF;       // conv3b out / x (1,179,648)
    float* part = A + 13 * MF;       // lin1 partials  (2,097,152)
    float* x1   = A + 16 * MF;       // 32768
    float* x2   = x1 + 64 * HIDLINc; // 32768
    float* prep = x2 + 64 * HIDLINc; // 1536
    int*   pts  = (int*)(prep + 2048);

    // conv1a: image(64,3,96,96) -> A(64,32,96,96)
    conv96_v6<3, 3><<<dim3(36, 64), 256, 0, stream>>>(image, w1a, b1a, A);
    // conv1b: A -> B (64,32,96,96)
    conv96_v6<32, 8><<<dim3(36, 64), 256, 0, stream>>>(A, w1b, b1b, Bf);
    // pool 4x4: B -> t0 (64,32,24,24)
    maxpool_k<32, 96, 96, 4>
        <<<(BB * 32 * 24 * 24 + 255) / 256, 256, 0, stream>>>(Bf, t0);

    // conv2a: t0 -> partial(B) -> t1 (64,64,24,24); KS=2
    conv3x3_split<32, 64, 24, 24, 8, 24, 2>
        <<<dim3(3, 64, 2 * 2), 192, 0, stream>>>(t0, w2a, Bf);
    conv_reduce<64, 24, 24, 2>
        <<<(BB * 64 * 576 + 255) / 256, 256, 0, stream>>>(Bf, b2a, t1);

    // conv2b: t1 -> partial(B) -> t2; KS=4
    conv3x3_split<64, 64, 24, 24, 8, 24, 4>
        <<<dim3(3, 64, 2 * 4), 192, 0, stream>>>(t1, w2b, Bf);
    conv_reduce<64, 24, 24, 4>
        <<<(BB * 64 * 576 + 255) / 256, 256, 0, stream>>>(Bf, b2b, t2);

    // pool 2x2: t2 -> t3 (64,64,12,12)
    maxpool_k<64, 24, 24, 2>
        <<<(BB * 64 * 12 * 12 + 255) / 256, 256, 0, stream>>>(t2, t3);

    // conv3a: t3 -> partial(B) -> t4 (64,128,12,12); KS=4
    conv3x3_split<64, 128, 12, 12, 12, 12, 4>
        <<<dim3(1, 64, 4 * 4), 144, 0, stream>>>(t3, w3a, Bf);
    conv_reduce<128, 12, 12, 4>
        <<<(BB * 128 * 144 + 255) / 256, 256, 0, stream>>>(Bf, b3a, t4);

    // conv3b: t4 -> partial(B) -> t5; KS=8
    conv3x3_split<128, 128, 12, 12, 12, 12, 8>
        <<<dim3(1, 64, 4 * 8), 144, 0, stream>>>(t4, w3b, Bf);
    conv_reduce<128, 12, 12, 8>
        <<<(BB * 128 * 144 + 255) / 256, 256, 0, stream>>>(Bf, b3b, t5);

    // lin1: x @ wl1 (+bl1, relu) via split-K
    lin1_partial<<<dim3(8, KSPLIT), 256, 0, stream>>>(t5, wl1, part);
    lin1_reduce<<<(64 * HIDLINc + 255) / 256, 256, 0, stream>>>(part, bl1, x1);
    // lin2
    lin2_k<<<dim3(8, 16), 256, 0, stream>>>(x1, wl2, bl2, x2);
    // lin3 -> prep (64,24)
    lin3_k<<<6, 256, 0, stream>>>(x2, wl3, bl3, prep);
    // head -> means/sigmas into out, pts into ws
    head_k<<<2, 256, 0, stream>>>(prep, noise,
                                  out + (size_t)BB * Gc * CIc * HGc * WGc,
                                  out + (size_t)BB * Gc * CIc * HGc * WGc + BB * Gc * 2,
                                  pts);
    // patch extraction -> out[0 .. 393216)
    patch_k<<<BB * Gc, 256, 0, stream>>>(image, pts, out);
}

// Round 8
// 654.674 us; speedup vs baseline: 2.3557x; 1.3243x over previous
//
#include <hip/hip_runtime.h>
#include <math.h>

// Problem constants
constexpr int BB  = 64;    // batch
constexpr int CIc = 3;     // image channels
constexpr int HIc = 96, WIc = 96;
constexpr int Gc  = 8, HGc = 16, WGc = 16;
constexpr int HIDc = 18432;      // 128*12*12
constexpr int HIDLINc = 512;

using short8 = __attribute__((ext_vector_type(8))) short;
using f32x16 = __attribute__((ext_vector_type(16))) float;

// bf16 split helpers (RNE)
__device__ inline unsigned short bfr(float f) {
    unsigned int u = __float_as_uint(f);
    u = (u + 0x7FFFu + ((u >> 16) & 1u)) >> 16;
    return (unsigned short)u;
}
__device__ inline float ubf(unsigned short s) {
    return __uint_as_float(((unsigned int)s) << 16);
}

// Packed conv1b weight tables: [s=18][g=2][oc=32][j=8] bf16, k = s*16+g*8+j,
// ci = 16*(s&1)+8*g+j, tap = s>>1 (dy=tap/3, dx=tap%3).
__device__ __attribute__((aligned(16))) unsigned short g_wh[18432];
__device__ __attribute__((aligned(16))) unsigned short g_wm[18432];
__device__ __attribute__((aligned(16))) unsigned short g_wl[18432];

__global__ void pack_w1b(const float* __restrict__ w)
{
    int idx = blockIdx.x * 256 + threadIdx.x;
    if (idx >= 18432) return;
    int j = idx & 7, oc = (idx >> 3) & 31, g = (idx >> 8) & 1, s = idx >> 9;
    int ci = 16 * (s & 1) + 8 * g + j;
    int tap = s >> 1;
    float v = w[(oc * 32 + ci) * 9 + tap];
    unsigned short h = bfr(v);
    float r1 = v - ubf(h);
    unsigned short m = bfr(r1);
    float r2 = r1 - ubf(m);
    unsigned short l = bfr(r2);
    g_wh[idx] = h; g_wm[idx] = m; g_wl[idx] = l;
}

// Zero the padded borders of the packed X tensors [64][98][98][32]
__global__ void border_zero(unsigned short* __restrict__ Xh,
                            unsigned short* __restrict__ Xm,
                            unsigned short* __restrict__ Xl)
{
    int idx = blockIdx.x * 256 + threadIdx.x;
    constexpr int TOT = 64 * 388 * 32;
    if (idx >= TOT) return;
    int ci = idx & 31;
    int c  = (idx >> 5) % 388;
    int b  = idx / (388 * 32);
    int y, x;
    if (c < 98)       { y = 0;  x = c; }
    else if (c < 196) { y = 97; x = c - 98; }
    else { int t = c - 196; y = 1 + (t >> 1); x = (t & 1) ? 97 : 0; }
    size_t a = ((size_t)(b * 98 + y) * 98 + x) * 32 + ci;
    Xh[a] = 0; Xm[a] = 0; Xl[a] = 0;
}

// ---------------------------------------------------------------------------
// conv1a_pack: 3x3 conv pad=1 (CIN=3) + bias + ReLU, output written as
// 3-way bf16 decomposition into padded channel-last tensors X{h,m,l}
// [b][y+1][x+1][ci]. Tile 32x8, 256 thr, 1 px x 32 oc per thread.
// ---------------------------------------------------------------------------
__global__ __launch_bounds__(256)
void conv1a_pack(const float* __restrict__ in, const float* __restrict__ wgt,
                 const float* __restrict__ bias,
                 unsigned short* __restrict__ Xh, unsigned short* __restrict__ Xm,
                 unsigned short* __restrict__ Xl)
{
    const int txi = blockIdx.x % 3, tyi = blockIdx.x / 3;   // 3 x 12 tiles
    const int ox = txi * 32, oy = tyi * 8;
    const int b = blockIdx.y;
    const int tid = threadIdx.x;
    const int px = tid & 31;
    const int py = tid >> 5;

    __shared__ float s_in[3][10][34];

    float acc[32];
#pragma unroll
    for (int oc = 0; oc < 32; ++oc) acc[oc] = 0.0f;

    {
        constexpr int TOT = 3 * 10 * 34;
        for (int idx = tid; idx < TOT; idx += 256) {
            int ci  = idx / 340;
            int rem = idx - ci * 340;
            int r = rem / 34;
            int c = rem - r * 34;
            int gy = oy + r - 1, gx = ox + c - 1;
            float v = 0.0f;
            if (gy >= 0 && gy < 96 && gx >= 0 && gx < 96)
                v = in[((size_t)(b * 3 + ci) * 96 + gy) * 96 + gx];
            s_in[ci][r][c] = v;
        }
        __syncthreads();

        for (int ci = 0; ci < 3; ++ci) {
            float v[3][3];
#pragma unroll
            for (int r = 0; r < 3; ++r)
#pragma unroll
                for (int c = 0; c < 3; ++c)
                    v[r][c] = s_in[ci][py + r][px + c];

#pragma unroll
            for (int oc = 0; oc < 32; ++oc) {
                const float* w9 = wgt + ((size_t)oc * 3 + ci) * 9;
                float a = acc[oc];
#pragma unroll
                for (int dy = 0; dy < 3; ++dy)
#pragma unroll
                    for (int dx = 0; dx < 3; ++dx)
                        a = fmaf(v[dy][dx], w9[dy * 3 + dx], a);
                acc[oc] = a;
            }
        }
    }

    // epilogue: relu + 3-way bf16 split, channel-last packed store
    size_t base = ((size_t)(b * 98 + oy + py + 1) * 98 + (ox + px + 1)) * 32;
#pragma unroll
    for (int q = 0; q < 4; ++q) {
        unsigned short H[8], M[8], L[8];
#pragma unroll
        for (int i = 0; i < 8; ++i) {
            int oc = q * 8 + i;
            float v = fmaxf(acc[oc] + bias[oc], 0.0f);
            unsigned short h = bfr(v);
            float r1 = v - ubf(h);
            unsigned short m = bfr(r1);
            float r2 = r1 - ubf(m);
            H[i] = h; M[i] = m; L[i] = bfr(r2);
        }
        *(short8*)(Xh + base + q * 8) = *(short8*)H;
        *(short8*)(Xm + base + q * 8) = *(short8*)M;
        *(short8*)(Xl + base + q * 8) = *(short8*)L;
    }
}

// ---------------------------------------------------------------------------
// conv1b_mfma: implicit-GEMM 3x3 conv via v_mfma_f32_32x32x16_bf16 with
// 3x3 bf16 decomposition (6 kept products: hH,mH,lH,hM,mM,hL ~ fp32-exact).
// Wave tile: 32 oc x 32 pixels (one row segment). Block = 4 waves = 4 rows,
// fused 4x4 maxpool epilogue -> pool1 output [64][32][24][24].
// K=288 ordered k=tap*32+ci: each fragment slice = 8 contiguous ci ->
// single b128 load from packed channel-last X. Grid (3 xt, 24 yq, 64 b).
// ---------------------------------------------------------------------------
__global__ __launch_bounds__(256)
void conv1b_mfma(const unsigned short* __restrict__ Xh,
                 const unsigned short* __restrict__ Xm,
                 const unsigned short* __restrict__ Xl,
                 const float* __restrict__ bias, float* __restrict__ t0)
{
    const int xt = blockIdx.x, yq = blockIdx.y, b = blockIdx.z;
    const int tid = threadIdx.x;
    const int wave = tid >> 6, lane = tid & 63;
    const int col = lane & 31, g = lane >> 5;
    const int y = yq * 4 + wave;
    const int x0 = xt * 32;

    __shared__ float sp[32][4][33];
    __shared__ float s_bias[32];
    if (tid < 32) s_bias[tid] = bias[tid];
    __syncthreads();

    // per-lane base into packed X: stored row (y+dy), stored col (x0+col+dx)
    const size_t ib = ((size_t)(b * 98 + y) * 98 + (x0 + col)) * 32 + g * 8;

    f32x16 acc0 = {0,0,0,0,0,0,0,0,0,0,0,0,0,0,0,0};
    f32x16 acc1 = {0,0,0,0,0,0,0,0,0,0,0,0,0,0,0,0};

#pragma unroll
    for (int s = 0; s < 18; ++s) {
        const int tap = s >> 1;
        const int dy = tap / 3, dx = tap % 3;
        const int off = (dy * 98 + dx) * 32 + (s & 1) * 16;
        const int aidx = s * 512 + g * 256 + col * 8;

        short8 ah = *(const short8*)(g_wh + aidx);
        short8 am = *(const short8*)(g_wm + aidx);
        short8 al = *(const short8*)(g_wl + aidx);
        short8 bh = *(const short8*)(Xh + ib + off);
        short8 bm = *(const short8*)(Xm + ib + off);
        short8 bl = *(const short8*)(Xl + ib + off);

        acc0 = __builtin_amdgcn_mfma_f32_32x32x16_bf16(ah, bh, acc0, 0, 0, 0);
        acc0 = __builtin_amdgcn_mfma_f32_32x32x16_bf16(am, bh, acc0, 0, 0, 0);
        acc0 = __builtin_amdgcn_mfma_f32_32x32x16_bf16(al, bh, acc0, 0, 0, 0);
        acc1 = __builtin_amdgcn_mfma_f32_32x32x16_bf16(ah, bm, acc1, 0, 0, 0);
        acc1 = __builtin_amdgcn_mfma_f32_32x32x16_bf16(am, bm, acc1, 0, 0, 0);
        acc1 = __builtin_amdgcn_mfma_f32_32x32x16_bf16(ah, bl, acc1, 0, 0, 0);
    }

    // epilogue: bias + relu into LDS pool buffer
#pragma unroll
    for (int r = 0; r < 16; ++r) {
        int ocr = (r & 3) + 8 * (r >> 2) + 4 * g;
        float v = acc0[r] + acc1[r] + s_bias[ocr];
        sp[ocr][wave][col] = fmaxf(v, 0.0f);
    }
    __syncthreads();

    // 4x4 maxpool: 256 threads -> (oc, xq)
    {
        int oc = tid >> 3, xq = tid & 7;
        float m = -INFINITY;
#pragma unroll
        for (int sy = 0; sy < 4; ++sy)
#pragma unroll
            for (int sx = 0; sx < 4; ++sx)
                m = fmaxf(m, sp[oc][sy][xq * 4 + sx]);
        t0[((size_t)(b * 32 + oc) * 24 + yq) * 24 + xt * 8 + xq] = m;
    }
}

// ---------------------------------------------------------------------------
// Split-K direct 3x3 conv (round-2 form): partials [KS][B][COUT][H][W].
// ---------------------------------------------------------------------------
template<int CIN, int COUT, int H, int W, int TH, int TW, int KS>
__global__ __launch_bounds__(TH * TW)
void conv3x3_split(const float* __restrict__ in, const float* __restrict__ wgt,
                   float* __restrict__ partial)
{
    constexpr int CBLK = CIN / KS;
    constexpr int NTX = W / TW;
    const int tx = blockIdx.x % NTX, ty = blockIdx.x / NTX;
    const int b  = blockIdx.y;
    const int chunk = blockIdx.z / KS;
    const int ks    = blockIdx.z % KS;
    const int coutBase = chunk * 32;
    const int cinBase  = ks * CBLK;
    const int tid = threadIdx.x;
    const int px = tid % TW, py = tid / TW;
    const int ox = tx * TW, oy = ty * TH;

    __shared__ float s_in[CBLK][TH + 2][TW + 2];

    constexpr int TOT = CBLK * (TH + 2) * (TW + 2);
    for (int idx = tid; idx < TOT; idx += TH * TW) {
        int ci  = idx / ((TH + 2) * (TW + 2));
        int rem = idx % ((TH + 2) * (TW + 2));
        int yy = rem / (TW + 2), xx = rem % (TW + 2);
        int gy = oy + yy - 1, gx = ox + xx - 1;
        float v = 0.0f;
        if (gy >= 0 && gy < H && gx >= 0 && gx < W)
            v = in[((size_t)(b * CIN + cinBase + ci) * H + gy) * W + gx];
        s_in[ci][yy][xx] = v;
    }
    __syncthreads();

    float acc[32];
#pragma unroll
    for (int oc = 0; oc < 32; ++oc) acc[oc] = 0.0f;

    for (int ci = 0; ci < CBLK; ++ci) {
        float v[9];
#pragma unroll
        for (int dy = 0; dy < 3; ++dy)
#pragma unroll
            for (int dx = 0; dx < 3; ++dx)
                v[dy * 3 + dx] = s_in[ci][py + dy][px + dx];

#pragma unroll
        for (int oc = 0; oc < 32; ++oc) {
            const float* w9 =
                wgt + ((size_t)(coutBase + oc) * CIN + (cinBase + ci)) * 9;
#pragma unroll
            for (int k = 0; k < 9; ++k)
                acc[oc] = fmaf(v[k], w9[k], acc[oc]);
        }
    }

#pragma unroll
    for (int oc = 0; oc < 32; ++oc) {
        partial[(((size_t)ks * BB + b) * COUT + coutBase + oc) * (H * W) +
                (oy + py) * W + ox + px] = acc[oc];
    }
}

// Sum split-K partials + bias + ReLU
template<int C, int H, int W, int KS>
__global__ void conv_reduce(const float* __restrict__ partial,
                            const float* __restrict__ bias,
                            float* __restrict__ out)
{
    constexpr int TOTAL = BB * C * H * W;
    int idx = blockIdx.x * blockDim.x + threadIdx.x;
    if (idx >= TOTAL) return;
    int c = (idx / (H * W)) % C;
    float s = bias[c];
#pragma unroll
    for (int k = 0; k < KS; ++k)
        s += partial[(size_t)k * TOTAL + idx];
    out[idx] = fmaxf(s, 0.0f);
}

// ---------------------------------------------------------------------------
// Max pool KxK, stride K
// ---------------------------------------------------------------------------
template<int C, int H, int W, int K>
__global__ void maxpool_k(const float* __restrict__ in, float* __restrict__ out)
{
    constexpr int HO = H / K, WO = W / K;
    int idx = blockIdx.x * blockDim.x + threadIdx.x;
    constexpr int TOTAL = BB * C * HO * WO;
    if (idx >= TOTAL) return;
    int wo = idx % WO; int t = idx / WO;
    int ho = t % HO; t /= HO;
    int c = t % C; int b = t / C;
    const float* p = in + ((size_t)(b * C + c) * H + ho * K) * W + wo * K;
    float m = -INFINITY;
#pragma unroll
    for (int i = 0; i < K; ++i)
#pragma unroll
        for (int j = 0; j < K; ++j)
            m = fmaxf(m, p[i * W + j]);
    out[idx] = m;
}

// ---------------------------------------------------------------------------
// lin1: (64, 18432) @ (18432, 512), split-K partials.
// ---------------------------------------------------------------------------
constexpr int KSPLIT = 64;              // 18432 / 64 = 288 per split
__global__ __launch_bounds__(256)
void lin1_partial(const float* __restrict__ x, const float* __restrict__ w,
                  float* __restrict__ partial)
{
    const int j  = threadIdx.x % 64;
    const int bg = threadIdx.x / 64;          // 0..3
    const int jBase = blockIdx.x * 64;        // 8 tiles of 64
    const int k  = blockIdx.y;                // 0..63
    const int i0 = k * 288;

    __shared__ float s_x[32][64];

    float acc[16];
#pragma unroll
    for (int u = 0; u < 16; ++u) acc[u] = 0.0f;

    for (int ib = 0; ib < 288; ib += 32) {
        __syncthreads();
        {
            int lb = threadIdx.x / 4;           // b 0..63
            int lo = (threadIdx.x % 4) * 8;     // ii 0,8,16,24
            const float* src = x + (size_t)lb * HIDc + i0 + ib + lo;
            float4 a0 = *(const float4*)(src);
            float4 a1 = *(const float4*)(src + 4);
            float tmp[8] = {a0.x, a0.y, a0.z, a0.w, a1.x, a1.y, a1.z, a1.w};
#pragma unroll
            for (int r = 0; r < 8; ++r) s_x[lo + r][lb] = tmp[r];
        }
        __syncthreads();

        for (int ii = 0; ii < 32; ++ii) {
            float wv = w[(size_t)(i0 + ib + ii) * HIDLINc + jBase + j];
            const float4* xp = (const float4*)&s_x[ii][bg * 16];
            float4 x0 = xp[0], x1 = xp[1], x2 = xp[2], x3 = xp[3];
            acc[0]  = fmaf(x0.x, wv, acc[0]);
            acc[1]  = fmaf(x0.y, wv, acc[1]);
            acc[2]  = fmaf(x0.z, wv, acc[2]);
            acc[3]  = fmaf(x0.w, wv, acc[3]);
            acc[4]  = fmaf(x1.x, wv, acc[4]);
            acc[5]  = fmaf(x1.y, wv, acc[5]);
            acc[6]  = fmaf(x1.z, wv, acc[6]);
            acc[7]  = fmaf(x1.w, wv, acc[7]);
            acc[8]  = fmaf(x2.x, wv, acc[8]);
            acc[9]  = fmaf(x2.y, wv, acc[9]);
            acc[10] = fmaf(x2.z, wv, acc[10]);
            acc[11] = fmaf(x2.w, wv, acc[11]);
            acc[12] = fmaf(x3.x, wv, acc[12]);
            acc[13] = fmaf(x3.y, wv, acc[13]);
            acc[14] = fmaf(x3.z, wv, acc[14]);
            acc[15] = fmaf(x3.w, wv, acc[15]);
        }
    }

#pragma unroll
    for (int u = 0; u < 16; ++u) {
        int b = bg * 16 + u;
        partial[((size_t)k * 64 + b) * HIDLINc + jBase + j] = acc[u];
    }
}

__global__ void lin1_reduce(const float* __restrict__ partial,
                            const float* __restrict__ bias,
                            float* __restrict__ x1)
{
    int idx = blockIdx.x * blockDim.x + threadIdx.x;  // 64*512
    if (idx >= 64 * HIDLINc) return;
    int j = idx % HIDLINc;
    float s = 0.0f;
    for (int k = 0; k < KSPLIT; ++k)
        s += partial[(size_t)k * 64 * HIDLINc + idx];
    x1[idx] = fmaxf(s + bias[j], 0.0f);
}

// ---------------------------------------------------------------------------
// lin2: (64,512) @ (512,512) + bias + relu
// ---------------------------------------------------------------------------
__global__ __launch_bounds__(256)
void lin2_k(const float* __restrict__ x1, const float* __restrict__ w,
            const float* __restrict__ bias, float* __restrict__ x2)
{
    const int j  = threadIdx.x % 64;
    const int bl = threadIdx.x / 64;          // 0..3
    const int jBase = blockIdx.x * 64;        // 8
    const int b = blockIdx.y * 4 + bl;        // 16 groups of 4

    __shared__ float s_x[4][HIDLINc];
    for (int idx = threadIdx.x; idx < 4 * HIDLINc; idx += 256)
        s_x[idx / HIDLINc][idx % HIDLINc] =
            x1[(size_t)(blockIdx.y * 4 + idx / HIDLINc) * HIDLINc + idx % HIDLINc];
    __syncthreads();

    float acc = 0.0f;
    for (int i = 0; i < HIDLINc; ++i)
        acc = fmaf(s_x[bl][i], w[(size_t)i * HIDLINc + jBase + j], acc);
    x2[(size_t)b * HIDLINc + jBase + j] = fmaxf(acc + bias[jBase + j], 0.0f);
}

// ---------------------------------------------------------------------------
// lin3: (64,512) @ (512,24) + bias
// ---------------------------------------------------------------------------
__global__ void lin3_k(const float* __restrict__ x2, const float* __restrict__ w,
                       const float* __restrict__ bias, float* __restrict__ prep)
{
    int idx = blockIdx.x * blockDim.x + threadIdx.x;
    if (idx >= 64 * 24) return;
    int j = idx % 24, b = idx / 24;
    float acc = bias[j];
    for (int i = 0; i < HIDLINc; ++i)
        acc = fmaf(x2[(size_t)b * HIDLINc + i], w[i * 24 + j], acc);
    prep[idx] = acc;
}

// ---------------------------------------------------------------------------
// Head: means/sigmas/sample/points.  round = half-to-even (rintf)
// ---------------------------------------------------------------------------
__global__ void head_k(const float* __restrict__ prep, const float* __restrict__ noise,
                       float* __restrict__ outMeans, float* __restrict__ outSigmas,
                       int* __restrict__ pts)
{
    int id = blockIdx.x * blockDim.x + threadIdx.x;
    if (id >= BB * Gc) return;
    float m0 = prep[id * 3 + 0];
    float m1 = prep[id * 3 + 1];
    float sraw = prep[id * 3 + 2];
    float s = sraw + 2.0f;                       // SIGMA_BOOST
    float sig = fmaxf(s, 0.0f) + log1pf(expf(-fabsf(s)));
    sig += 1e-7f;                                // EPS
    float sg = sig * 95.0f;                      // (HI-1) == (WI-1)
    outMeans[id * 2 + 0] = m0;
    outMeans[id * 2 + 1] = m1;
    outSigmas[id * 2 + 0] = sg;
    outSigmas[id * 2 + 1] = sg;
    float sa0 = m0 + sg * noise[id * 2 + 0];
    float sa1 = m1 + sg * noise[id * 2 + 1];
    float t0 = 1.0f / (1.0f + expf(-sa0));
    float t1 = 1.0f / (1.0f + expf(-sa1));
    pts[id * 2 + 0] = (int)rintf(t0 * 79.0f);    // HI-HG-1
    pts[id * 2 + 1] = (int)rintf(t1 * 79.0f);    // WI-WG-1
}

// ---------------------------------------------------------------------------
// Patch extraction: copy (3,16,16) patch per (b,g)
// ---------------------------------------------------------------------------
__global__ __launch_bounds__(256)
void patch_k(const float* __restrict__ image, const int* __restrict__ pts,
             float* __restrict__ outR)
{
    int id = blockIdx.x;                  // b*G + g
    int b = id / Gc;
    int p0 = pts[id * 2 + 0];
    int p1 = pts[id * 2 + 1];
    for (int idx = threadIdx.x; idx < CIc * HGc * WGc; idx += 256) {
        int c = idx / (HGc * WGc), rem = idx % (HGc * WGc);
        int hh = rem / WGc, ww = rem % WGc;
        outR[(size_t)id * (CIc * HGc * WGc) + idx] =
            image[((size_t)(b * CIc + c) * HIc + p0 + hh) * WIc + p1 + ww];
    }
}

// ---------------------------------------------------------------------------
extern "C" void kernel_launch(void* const* d_in, const int* in_sizes, int n_in,
                              void* d_out, int out_size, void* d_ws, size_t ws_size,
                              hipStream_t stream)
{
    const float* image = (const float*)d_in[0];
    const float* noise = (const float*)d_in[1];
    const float* w1a = (const float*)d_in[2];
    const float* b1a = (const float*)d_in[3];
    const float* w1b = (const float*)d_in[4];
    const float* b1b = (const float*)d_in[5];
    const float* w2a = (const float*)d_in[6];
    const float* b2a = (const float*)d_in[7];
    const float* w2b = (const float*)d_in[8];
    const float* b2b = (const float*)d_in[9];
    const float* w3a = (const float*)d_in[10];
    const float* b3a = (const float*)d_in[11];
    const float* w3b = (const float*)d_in[12];
    const float* b3b = (const float*)d_in[13];
    const float* wl1 = (const float*)d_in[14];
    const float* bl1 = (const float*)d_in[15];
    const float* wl2 = (const float*)d_in[16];
    const float* bl2 = (const float*)d_in[17];
    const float* wl3 = (const float*)d_in[18];
    const float* bl3 = (const float*)d_in[19];

    float* out = (float*)d_out;
    float* ws  = (float*)d_ws;

    // Workspace layout (float units). Packed X tensors then staged tensors.
    constexpr size_t MF = 1u << 20;
    unsigned short* Xh = (unsigned short*)(ws);             //  9.38MF span
    unsigned short* Xm = (unsigned short*)(ws + 10 * MF);
    unsigned short* Xl = (unsigned short*)(ws + 20 * MF);
    float* t0   = ws + 30 * MF;      // pool1 out (1.125MF) -- survives X reuse
    float* P    = ws;                // conv partials (<=9.44MF), X dead by then
    float* t1   = ws + 10 * MF;      // conv2a out (2.25MF)
    float* t2   = ws + 13 * MF;      // conv2b out (2.25MF)
    float* t3   = ws + 16 * MF;      // pool2 out (0.57MF)
    float* t4   = ws + 17 * MF;      // conv3a out (1.125MF)
    float* t5   = ws + 19 * MF;      // conv3b out / x (1.125MF)
    float* part = ws + 21 * MF;      // lin1 partials (2MF)
    float* x1   = ws + 24 * MF;      // 32768
    float* x2   = x1 + 64 * HIDLINc; // 32768
    float* prep = x2 + 64 * HIDLINc; // 1536
    int*   pts  = (int*)(prep + 2048);

    // weight pack + X border zero
    pack_w1b<<<(18432 + 255) / 256, 256, 0, stream>>>(w1b);
    border_zero<<<(64 * 388 * 32 + 255) / 256, 256, 0, stream>>>(Xh, Xm, Xl);

    // conv1a: image -> packed bf16 X (h/m/l), relu+bias applied
    conv1a_pack<<<dim3(36, 64), 256, 0, stream>>>(image, w1a, b1a, Xh, Xm, Xl);

    // conv1b (MFMA) + fused 4x4 maxpool: X -> t0 (64,32,24,24)
    conv1b_mfma<<<dim3(3, 24, 64), 256, 0, stream>>>(Xh, Xm, Xl, b1b, t0);

    // conv2a: t0 -> partial(P) -> t1 (64,64,24,24); KS=2
    conv3x3_split<32, 64, 24, 24, 8, 24, 2>
        <<<dim3(3, 64, 2 * 2), 192, 0, stream>>>(t0, w2a, P);
    conv_reduce<64, 24, 24, 2>
        <<<(BB * 64 * 576 + 255) / 256, 256, 0, stream>>>(P, b2a, t1);

    // conv2b: t1 -> partial(P) -> t2; KS=4
    conv3x3_split<64, 64, 24, 24, 8, 24, 4>
        <<<dim3(3, 64, 2 * 4), 192, 0, stream>>>(t1, w2b, P);
    conv_reduce<64, 24, 24, 4>
        <<<(BB * 64 * 576 + 255) / 256, 256, 0, stream>>>(P, b2b, t2);

    // pool 2x2: t2 -> t3 (64,64,12,12)
    maxpool_k<64, 24, 24, 2>
        <<<(BB * 64 * 12 * 12 + 255) / 256, 256, 0, stream>>>(t2, t3);

    // conv3a: t3 -> partial(P) -> t4 (64,128,12,12); KS=4
    conv3x3_split<64, 128, 12, 12, 12, 12, 4>
        <<<dim3(1, 64, 4 * 4), 144, 0, stream>>>(t3, w3a, P);
    conv_reduce<128, 12, 12, 4>
        <<<(BB * 128 * 144 + 255) / 256, 256, 0, stream>>>(P, b3a, t4);

    // conv3b: t4 -> partial(P) -> t5; KS=8
    conv3x3_split<128, 128, 12, 12, 12, 12, 8>
        <<<dim3(1, 64, 4 * 8), 144, 0, stream>>>(t4, w3b, P);
    conv_reduce<128, 12, 12, 8>
        <<<(BB * 128 * 144 + 255) / 256, 256, 0, stream>>>(P, b3b, t5);

    // lin1: x @ wl1 (+bl1, relu) via split-K
    lin1_partial<<<dim3(8, KSPLIT), 256, 0, stream>>>(t5, wl1, part);
    lin1_reduce<<<(64 * HIDLINc + 255) / 256, 256, 0, stream>>>(part, bl1, x1);
    // lin2
    lin2_k<<<dim3(8, 16), 256, 0, stream>>>(x1, wl2, bl2, x2);
    // lin3 -> prep (64,24)
    lin3_k<<<6, 256, 0, stream>>>(x2, wl3, bl3, prep);
    // head -> means/sigmas into out, pts into ws
    head_k<<<2, 256, 0, stream>>>(prep, noise,
                                  out + (size_t)BB * Gc * CIc * HGc * WGc,
                                  out + (size_t)BB * Gc * CIc * HGc * WGc + BB * Gc * 2,
                                  pts);
    // patch extraction -> out[0 .. 393216)
    patch_k<<<BB * Gc, 256, 0, stream>>>(image, pts, out);
}

// Round 9
// 450.421 us; speedup vs baseline: 3.4239x; 1.4535x over previous
//
#include <hip/hip_runtime.h>
#include <math.h>

// Problem constants
constexpr int BB  = 64;
constexpr int CIc = 3;
constexpr int HIc = 96, WIc = 96;
constexpr int Gc  = 8, HGc = 16, WGc = 16;
constexpr int HIDc = 18432;
constexpr int HIDLINc = 512;

using short8 = __attribute__((ext_vector_type(8))) short;
using s4     = __attribute__((ext_vector_type(4))) short;
using f32x16 = __attribute__((ext_vector_type(16))) float;

// bf16 split helpers (RNE)
__device__ inline unsigned short bfr(float f) {
    unsigned int u = __float_as_uint(f);
    u = (u + 0x7FFFu + ((u >> 16) & 1u)) >> 16;
    return (unsigned short)u;
}
__device__ inline float ubf(unsigned short s) {
    return __uint_as_float(((unsigned int)s) << 16);
}

// conv1b weight tables: [s=18][g=2][oc=32][j=8], k = s*16+g*8+j = tap*32+ci
__device__ __attribute__((aligned(16))) unsigned short g_wh[9216];
__device__ __attribute__((aligned(16))) unsigned short g_wm[9216];
__device__ __attribute__((aligned(16))) unsigned short g_wl[9216];

// generic conv weight tables (conv2a/2b/3a/3b), layout per chunk:
// [s][g][oc32][j], k = tap*CIN + ci, ci = (s%NC16)*16 + g*8 + j
// offsets (shorts): 2a=0 (18432), 2b=18432 (36864), 3a=55296 (73728), 3b=129024 (147456)
__device__ __attribute__((aligned(16))) unsigned short g_wph[276480];
__device__ __attribute__((aligned(16))) unsigned short g_wpm[276480];
__device__ __attribute__((aligned(16))) unsigned short g_wpl[276480];

__global__ void pack_w1b(const float* __restrict__ w)
{
    int idx = blockIdx.x * 256 + threadIdx.x;
    if (idx >= 9216) return;
    int j = idx & 7, oc = (idx >> 3) & 31, g = (idx >> 8) & 1, s = idx >> 9;
    int ci = 16 * (s & 1) + 8 * g + j;
    int tap = s >> 1;
    float v = w[(oc * 32 + ci) * 9 + tap];
    unsigned short h = bfr(v);
    float r1 = v - ubf(h);
    unsigned short m = bfr(r1);
    g_wh[idx] = h; g_wm[idx] = m; g_wl[idx] = bfr(r1 - ubf(m));
}

__global__ void pack_wN(const float* __restrict__ w, int COUT, int CIN, int ofs)
{
    int idx = blockIdx.x * 256 + threadIdx.x;
    int total = COUT * CIN * 9;
    if (idx >= total) return;
    int chsz = 288 * CIN;
    int chunk = idx / chsz;
    int t = idx - chunk * chsz;
    int s = t >> 9;
    int rr = t & 511;
    int g = rr >> 8, oc32 = (rr >> 3) & 31, j = rr & 7;
    int nc16 = CIN / 16;
    int tap = s / nc16, c16 = s % nc16;
    int ci = c16 * 16 + g * 8 + j;
    int oc = chunk * 32 + oc32;
    float v = w[((size_t)oc * CIN + ci) * 9 + tap];
    unsigned short h = bfr(v);
    float r1 = v - ubf(h);
    unsigned short m = bfr(r1);
    g_wph[ofs + idx] = h; g_wpm[ofs + idx] = m; g_wpl[ofs + idx] = bfr(r1 - ubf(m));
}

// Zero the 1-px border ring of padded channel-last tensors [BB][PAD][PAD][C]
template<int PAD, int C>
__global__ void border_zero_p(unsigned short* __restrict__ Xh,
                              unsigned short* __restrict__ Xm,
                              unsigned short* __restrict__ Xl)
{
    constexpr int RING = 4 * PAD - 4;
    constexpr int TOT = BB * RING * C;
    int idx = blockIdx.x * 256 + threadIdx.x;
    if (idx >= TOT) return;
    int ci = idx % C;
    int cell = (idx / C) % RING;
    int b = idx / (C * RING);
    int y, x;
    if (cell < PAD)          { y = 0;       x = cell; }
    else if (cell < 2 * PAD) { y = PAD - 1; x = cell - PAD; }
    else { int t = cell - 2 * PAD; y = 1 + (t >> 1); x = (t & 1) ? PAD - 1 : 0; }
    size_t a = ((size_t)(b * PAD + y) * PAD + x) * C + ci;
    Xh[a] = 0; Xm[a] = 0; Xl[a] = 0;
}

// ---------------------------------------------------------------------------
// conv1a_pack: fp32 direct conv (CIN=3) + bias + ReLU, 3-way bf16 split into
// padded channel-last X1 [b][98][98][32].
// ---------------------------------------------------------------------------
__global__ __launch_bounds__(256)
void conv1a_pack(const float* __restrict__ in, const float* __restrict__ wgt,
                 const float* __restrict__ bias,
                 unsigned short* __restrict__ Xh, unsigned short* __restrict__ Xm,
                 unsigned short* __restrict__ Xl)
{
    const int txi = blockIdx.x % 3, tyi = blockIdx.x / 3;
    const int ox = txi * 32, oy = tyi * 8;
    const int b = blockIdx.y;
    const int tid = threadIdx.x;
    const int px = tid & 31;
    const int py = tid >> 5;

    __shared__ float s_in[3][10][34];

    float acc[32];
#pragma unroll
    for (int oc = 0; oc < 32; ++oc) acc[oc] = 0.0f;

    {
        constexpr int TOT = 3 * 10 * 34;
        for (int idx = tid; idx < TOT; idx += 256) {
            int ci  = idx / 340;
            int rem = idx - ci * 340;
            int r = rem / 34;
            int c = rem - r * 34;
            int gy = oy + r - 1, gx = ox + c - 1;
            float v = 0.0f;
            if (gy >= 0 && gy < 96 && gx >= 0 && gx < 96)
                v = in[((size_t)(b * 3 + ci) * 96 + gy) * 96 + gx];
            s_in[ci][r][c] = v;
        }
        __syncthreads();

        for (int ci = 0; ci < 3; ++ci) {
            float v[3][3];
#pragma unroll
            for (int r = 0; r < 3; ++r)
#pragma unroll
                for (int c = 0; c < 3; ++c)
                    v[r][c] = s_in[ci][py + r][px + c];

#pragma unroll
            for (int oc = 0; oc < 32; ++oc) {
                const float* w9 = wgt + ((size_t)oc * 3 + ci) * 9;
                float a = acc[oc];
#pragma unroll
                for (int dy = 0; dy < 3; ++dy)
#pragma unroll
                    for (int dx = 0; dx < 3; ++dx)
                        a = fmaf(v[dy][dx], w9[dy * 3 + dx], a);
                acc[oc] = a;
            }
        }
    }

    size_t base = ((size_t)(b * 98 + oy + py + 1) * 98 + (ox + px + 1)) * 32;
#pragma unroll
    for (int q = 0; q < 4; ++q) {
        unsigned short H[8], M[8], L[8];
#pragma unroll
        for (int i = 0; i < 8; ++i) {
            int oc = q * 8 + i;
            float v = fmaxf(acc[oc] + bias[oc], 0.0f);
            unsigned short h = bfr(v);
            float r1 = v - ubf(h);
            unsigned short m = bfr(r1);
            H[i] = h; M[i] = m; L[i] = bfr(r1 - ubf(m));
        }
        *(short8*)(Xh + base + q * 8) = *(short8*)H;
        *(short8*)(Xm + base + q * 8) = *(short8*)M;
        *(short8*)(Xl + base + q * 8) = *(short8*)L;
    }
}

// ---------------------------------------------------------------------------
// conv1b_mfma: implicit-GEMM 3x3 conv (32->32, 96x96) via mfma_32x32x16_bf16,
// fused 4x4 maxpool epilogue writing packed X2 [b][26][26][32] h/m/l.
// ---------------------------------------------------------------------------
__global__ __launch_bounds__(256)
void conv1b_mfma(const unsigned short* __restrict__ Xh,
                 const unsigned short* __restrict__ Xm,
                 const unsigned short* __restrict__ Xl,
                 const float* __restrict__ bias,
                 unsigned short* __restrict__ X2h, unsigned short* __restrict__ X2m,
                 unsigned short* __restrict__ X2l)
{
    const int xt = blockIdx.x, yq = blockIdx.y, b = blockIdx.z;
    const int tid = threadIdx.x;
    const int wave = tid >> 6, lane = tid & 63;
    const int col = lane & 31, g = lane >> 5;
    const int y = yq * 4 + wave;
    const int x0 = xt * 32;

    __shared__ float sp[32][4][33];
    __shared__ float s_bias[32];
    if (tid < 32) s_bias[tid] = bias[tid];
    __syncthreads();

    const size_t ib = ((size_t)(b * 98 + y) * 98 + (x0 + col)) * 32 + g * 8;

    f32x16 acc0 = {0,0,0,0,0,0,0,0,0,0,0,0,0,0,0,0};
    f32x16 acc1 = {0,0,0,0,0,0,0,0,0,0,0,0,0,0,0,0};

#pragma unroll
    for (int s = 0; s < 18; ++s) {
        const int tap = s >> 1;
        const int dy = tap / 3, dx = tap % 3;
        const int off = (dy * 98 + dx) * 32 + (s & 1) * 16;
        const int aidx = s * 512 + g * 256 + col * 8;

        short8 ah = *(const short8*)(g_wh + aidx);
        short8 am = *(const short8*)(g_wm + aidx);
        short8 al = *(const short8*)(g_wl + aidx);
        short8 bh = *(const short8*)(Xh + ib + off);
        short8 bm = *(const short8*)(Xm + ib + off);
        short8 bl = *(const short8*)(Xl + ib + off);

        acc0 = __builtin_amdgcn_mfma_f32_32x32x16_bf16(ah, bh, acc0, 0, 0, 0);
        acc1 = __builtin_amdgcn_mfma_f32_32x32x16_bf16(ah, bm, acc1, 0, 0, 0);
        acc0 = __builtin_amdgcn_mfma_f32_32x32x16_bf16(am, bh, acc0, 0, 0, 0);
        acc1 = __builtin_amdgcn_mfma_f32_32x32x16_bf16(am, bm, acc1, 0, 0, 0);
        acc0 = __builtin_amdgcn_mfma_f32_32x32x16_bf16(al, bh, acc0, 0, 0, 0);
        acc1 = __builtin_amdgcn_mfma_f32_32x32x16_bf16(ah, bl, acc1, 0, 0, 0);
    }

#pragma unroll
    for (int r = 0; r < 16; ++r) {
        int ocr = (r & 3) + 8 * (r >> 2) + 4 * g;
        float v = acc0[r] + acc1[r] + s_bias[ocr];
        sp[ocr][wave][col] = fmaxf(v, 0.0f);
    }
    __syncthreads();

    {
        int oc = tid & 31, xq = tid >> 5;      // 32 oc x 8 pooled cols
        float mv = -INFINITY;
#pragma unroll
        for (int sy = 0; sy < 4; ++sy)
#pragma unroll
            for (int sx = 0; sx < 4; ++sx)
                mv = fmaxf(mv, sp[oc][sy][xq * 4 + sx]);
        unsigned short h = bfr(mv);
        float r1 = mv - ubf(h);
        unsigned short m = bfr(r1);
        size_t oa = ((size_t)(b * 26 + yq + 1) * 26 + xt * 8 + xq + 1) * 32 + oc;
        X2h[oa] = h; X2m[oa] = m; X2l[oa] = bfr(r1 - ubf(m));
    }
}

// ---------------------------------------------------------------------------
// convN_mfma: generic implicit-GEMM 3x3 conv over padded channel-last packed
// input [b][HW+2][HW+2][CIN] h/m/l. Wave = 32 oc x 32 linear pixels (pixels
// span batches). OUTMODE 0: packed channel-last output (for next conv);
// OUTMODE 1: fp32 NCHW + ReLU. Fragment roles identical to conv1b (verified).
// ---------------------------------------------------------------------------
template<int CIN, int HW, int NCHUNK, int OUTMODE>
__global__ __launch_bounds__(256)
void convN_mfma(const unsigned short* __restrict__ Xh,
                const unsigned short* __restrict__ Xm,
                const unsigned short* __restrict__ Xl,
                int wofs, const float* __restrict__ bias,
                unsigned short* __restrict__ Yh,
                unsigned short* __restrict__ Ym,
                unsigned short* __restrict__ Yl,
                float* __restrict__ Yf)
{
    constexpr int PAD = HW + 2;
    constexpr int NC16 = CIN / 16;
    constexpr int CHSZ = 288 * CIN;
    constexpr int COUT = NCHUNK * 32;

    const int tid = threadIdx.x;
    const int wid = blockIdx.x * 4 + (tid >> 6);
    const int lane = tid & 63;
    const int col = lane & 31, g = lane >> 5;

    const int chunk = wid % NCHUNK;
    const int wt = wid / NCHUNK;
    const int P = wt * 32 + col;
    const int b = P / (HW * HW);
    const int rem = P - b * (HW * HW);
    const int y = rem / HW, x = rem - y * HW;

    const size_t ib = ((size_t)(b * PAD + y) * PAD + x) * CIN + g * 8;
    const int wbase = wofs + chunk * CHSZ;

    f32x16 acc0 = {0,0,0,0,0,0,0,0,0,0,0,0,0,0,0,0};
    f32x16 acc1 = {0,0,0,0,0,0,0,0,0,0,0,0,0,0,0,0};

#pragma unroll
    for (int tap = 0; tap < 9; ++tap) {
        const int dy = tap / 3, dx = tap % 3;
        for (int c16 = 0; c16 < NC16; ++c16) {
            const int s = tap * NC16 + c16;
            const int aidx = wbase + s * 512 + g * 256 + col * 8;
            const size_t xo = ib + (size_t)((dy * PAD + dx) * CIN + c16 * 16);
            short8 ah = *(const short8*)(g_wph + aidx);
            short8 am = *(const short8*)(g_wpm + aidx);
            short8 al = *(const short8*)(g_wpl + aidx);
            short8 bh = *(const short8*)(Xh + xo);
            short8 bm = *(const short8*)(Xm + xo);
            short8 bl = *(const short8*)(Xl + xo);
            acc0 = __builtin_amdgcn_mfma_f32_32x32x16_bf16(ah, bh, acc0, 0, 0, 0);
            acc1 = __builtin_amdgcn_mfma_f32_32x32x16_bf16(ah, bm, acc1, 0, 0, 0);
            acc0 = __builtin_amdgcn_mfma_f32_32x32x16_bf16(am, bh, acc0, 0, 0, 0);
            acc1 = __builtin_amdgcn_mfma_f32_32x32x16_bf16(am, bm, acc1, 0, 0, 0);
            acc0 = __builtin_amdgcn_mfma_f32_32x32x16_bf16(al, bh, acc0, 0, 0, 0);
            acc1 = __builtin_amdgcn_mfma_f32_32x32x16_bf16(ah, bl, acc1, 0, 0, 0);
        }
    }

    if constexpr (OUTMODE == 0) {
        const size_t obase =
            ((size_t)(b * PAD + y + 1) * PAD + (x + 1)) * COUT + chunk * 32;
#pragma unroll
        for (int q = 0; q < 4; ++q) {
            s4 H, M, L;
#pragma unroll
            for (int i = 0; i < 4; ++i) {
                int r = q * 4 + i;
                int ocr = i + 8 * q + 4 * g;
                float v = fmaxf(acc0[r] + acc1[r] + bias[chunk * 32 + ocr], 0.0f);
                unsigned short h = bfr(v);
                float r1 = v - ubf(h);
                unsigned short m = bfr(r1);
                H[i] = (short)h; M[i] = (short)m; L[i] = (short)bfr(r1 - ubf(m));
            }
            *(s4*)(Yh + obase + 8 * q + 4 * g) = H;
            *(s4*)(Ym + obase + 8 * q + 4 * g) = M;
            *(s4*)(Yl + obase + 8 * q + 4 * g) = L;
        }
    } else {
#pragma unroll
        for (int r = 0; r < 16; ++r) {
            int ocr = chunk * 32 + (r & 3) + 8 * (r >> 2) + 4 * g;
            float v = fmaxf(acc0[r] + acc1[r] + bias[ocr], 0.0f);
            Yf[((size_t)(b * COUT + ocr) * HW + y) * HW + x] = v;
        }
    }
}

// ---------------------------------------------------------------------------
// pool2_pack: 2x2 maxpool of t2 (64,64,24,24) fp32 -> packed X4 [b][14][14][64]
// ---------------------------------------------------------------------------
__global__ __launch_bounds__(256)
void pool2_pack(const float* __restrict__ t2,
                unsigned short* __restrict__ X4h,
                unsigned short* __restrict__ X4m,
                unsigned short* __restrict__ X4l)
{
    int idx = blockIdx.x * 256 + threadIdx.x;
    constexpr int TOT = BB * 144 * 64;
    if (idx >= TOT) return;
    int oc = idx & 63;
    int p = (idx >> 6) % 144;
    int b = idx / (144 * 64);
    int y = p / 12, x = p % 12;
    const float* src = t2 + ((size_t)(b * 64 + oc) * 24 + 2 * y) * 24 + 2 * x;
    float v = fmaxf(fmaxf(src[0], src[1]), fmaxf(src[24], src[25]));
    unsigned short h = bfr(v);
    float r1 = v - ubf(h);
    unsigned short m = bfr(r1);
    size_t oa = ((size_t)(b * 14 + y + 1) * 14 + x + 1) * 64 + oc;
    X4h[oa] = h; X4m[oa] = m; X4l[oa] = bfr(r1 - ubf(m));
}

// ---------------------------------------------------------------------------
// lin1: (64, 18432) @ (18432, 512), split-K partials.
// ---------------------------------------------------------------------------
constexpr int KSPLIT = 64;
__global__ __launch_bounds__(256)
void lin1_partial(const float* __restrict__ x, const float* __restrict__ w,
                  float* __restrict__ partial)
{
    const int j  = threadIdx.x % 64;
    const int bg = threadIdx.x / 64;
    const int jBase = blockIdx.x * 64;
    const int k  = blockIdx.y;
    const int i0 = k * 288;

    __shared__ float s_x[32][64];

    float acc[16];
#pragma unroll
    for (int u = 0; u < 16; ++u) acc[u] = 0.0f;

    for (int ib = 0; ib < 288; ib += 32) {
        __syncthreads();
        {
            int lb = threadIdx.x / 4;
            int lo = (threadIdx.x % 4) * 8;
            const float* src = x + (size_t)lb * HIDc + i0 + ib + lo;
            float4 a0 = *(const float4*)(src);
            float4 a1 = *(const float4*)(src + 4);
            float tmp[8] = {a0.x, a0.y, a0.z, a0.w, a1.x, a1.y, a1.z, a1.w};
#pragma unroll
            for (int r = 0; r < 8; ++r) s_x[lo + r][lb] = tmp[r];
        }
        __syncthreads();

        for (int ii = 0; ii < 32; ++ii) {
            float wv = w[(size_t)(i0 + ib + ii) * HIDLINc + jBase + j];
            const float4* xp = (const float4*)&s_x[ii][bg * 16];
            float4 x0 = xp[0], x1 = xp[1], x2 = xp[2], x3 = xp[3];
            acc[0]  = fmaf(x0.x, wv, acc[0]);
            acc[1]  = fmaf(x0.y, wv, acc[1]);
            acc[2]  = fmaf(x0.z, wv, acc[2]);
            acc[3]  = fmaf(x0.w, wv, acc[3]);
            acc[4]  = fmaf(x1.x, wv, acc[4]);
            acc[5]  = fmaf(x1.y, wv, acc[5]);
            acc[6]  = fmaf(x1.z, wv, acc[6]);
            acc[7]  = fmaf(x1.w, wv, acc[7]);
            acc[8]  = fmaf(x2.x, wv, acc[8]);
            acc[9]  = fmaf(x2.y, wv, acc[9]);
            acc[10] = fmaf(x2.z, wv, acc[10]);
            acc[11] = fmaf(x2.w, wv, acc[11]);
            acc[12] = fmaf(x3.x, wv, acc[12]);
            acc[13] = fmaf(x3.y, wv, acc[13]);
            acc[14] = fmaf(x3.z, wv, acc[14]);
            acc[15] = fmaf(x3.w, wv, acc[15]);
        }
    }

#pragma unroll
    for (int u = 0; u < 16; ++u) {
        int b = bg * 16 + u;
        partial[((size_t)k * 64 + b) * HIDLINc + jBase + j] = acc[u];
    }
}

__global__ void lin1_reduce(const float* __restrict__ partial,
                            const float* __restrict__ bias,
                            float* __restrict__ x1)
{
    int idx = blockIdx.x * blockDim.x + threadIdx.x;
    if (idx >= 64 * HIDLINc) return;
    int j = idx % HIDLINc;
    float s = 0.0f;
    for (int k = 0; k < KSPLIT; ++k)
        s += partial[(size_t)k * 64 * HIDLINc + idx];
    x1[idx] = fmaxf(s + bias[j], 0.0f);
}

__global__ __launch_bounds__(256)
void lin2_k(const float* __restrict__ x1, const float* __restrict__ w,
            const float* __restrict__ bias, float* __restrict__ x2)
{
    const int j  = threadIdx.x % 64;
    const int bl = threadIdx.x / 64;
    const int jBase = blockIdx.x * 64;
    const int b = blockIdx.y * 4 + bl;

    __shared__ float s_x[4][HIDLINc];
    for (int idx = threadIdx.x; idx < 4 * HIDLINc; idx += 256)
        s_x[idx / HIDLINc][idx % HIDLINc] =
            x1[(size_t)(blockIdx.y * 4 + idx / HIDLINc) * HIDLINc + idx % HIDLINc];
    __syncthreads();

    float acc = 0.0f;
    for (int i = 0; i < HIDLINc; ++i)
        acc = fmaf(s_x[bl][i], w[(size_t)i * HIDLINc + jBase + j], acc);
    x2[(size_t)b * HIDLINc + jBase + j] = fmaxf(acc + bias[jBase + j], 0.0f);
}

__global__ void lin3_k(const float* __restrict__ x2, const float* __restrict__ w,
                       const float* __restrict__ bias, float* __restrict__ prep)
{
    int idx = blockIdx.x * blockDim.x + threadIdx.x;
    if (idx >= 64 * 24) return;
    int j = idx % 24, b = idx / 24;
    float acc = bias[j];
    for (int i = 0; i < HIDLINc; ++i)
        acc = fmaf(x2[(size_t)b * HIDLINc + i], w[i * 24 + j], acc);
    prep[idx] = acc;
}

__global__ void head_k(const float* __restrict__ prep, const float* __restrict__ noise,
                       float* __restrict__ outMeans, float* __restrict__ outSigmas,
                       int* __restrict__ pts)
{
    int id = blockIdx.x * blockDim.x + threadIdx.x;
    if (id >= BB * Gc) return;
    float m0 = prep[id * 3 + 0];
    float m1 = prep[id * 3 + 1];
    float sraw = prep[id * 3 + 2];
    float s = sraw + 2.0f;
    float sig = fmaxf(s, 0.0f) + log1pf(expf(-fabsf(s)));
    sig += 1e-7f;
    float sg = sig * 95.0f;
    outMeans[id * 2 + 0] = m0;
    outMeans[id * 2 + 1] = m1;
    outSigmas[id * 2 + 0] = sg;
    outSigmas[id * 2 + 1] = sg;
    float sa0 = m0 + sg * noise[id * 2 + 0];
    float sa1 = m1 + sg * noise[id * 2 + 1];
    float t0 = 1.0f / (1.0f + expf(-sa0));
    float t1 = 1.0f / (1.0f + expf(-sa1));
    pts[id * 2 + 0] = (int)rintf(t0 * 79.0f);
    pts[id * 2 + 1] = (int)rintf(t1 * 79.0f);
}

__global__ __launch_bounds__(256)
void patch_k(const float* __restrict__ image, const int* __restrict__ pts,
             float* __restrict__ outR)
{
    int id = blockIdx.x;
    int b = id / Gc;
    int p0 = pts[id * 2 + 0];
    int p1 = pts[id * 2 + 1];
    for (int idx = threadIdx.x; idx < CIc * HGc * WGc; idx += 256) {
        int c = idx / (HGc * WGc), rem = idx % (HGc * WGc);
        int hh = rem / WGc, ww = rem % WGc;
        outR[(size_t)id * (CIc * HGc * WGc) + idx] =
            image[((size_t)(b * CIc + c) * HIc + p0 + hh) * WIc + p1 + ww];
    }
}

// ---------------------------------------------------------------------------
extern "C" void kernel_launch(void* const* d_in, const int* in_sizes, int n_in,
                              void* d_out, int out_size, void* d_ws, size_t ws_size,
                              hipStream_t stream)
{
    const float* image = (const float*)d_in[0];
    const float* noise = (const float*)d_in[1];
    const float* w1a = (const float*)d_in[2];
    const float* b1a = (const float*)d_in[3];
    const float* w1b = (const float*)d_in[4];
    const float* b1b = (const float*)d_in[5];
    const float* w2a = (const float*)d_in[6];
    const float* b2a = (const float*)d_in[7];
    const float* w2b = (const float*)d_in[8];
    const float* b2b = (const float*)d_in[9];
    const float* w3a = (const float*)d_in[10];
    const float* b3a = (const float*)d_in[11];
    const float* w3b = (const float*)d_in[12];
    const float* b3b = (const float*)d_in[13];
    const float* wl1 = (const float*)d_in[14];
    const float* bl1 = (const float*)d_in[15];
    const float* wl2 = (const float*)d_in[16];
    const float* bl2 = (const float*)d_in[17];
    const float* wl3 = (const float*)d_in[18];
    const float* bl3 = (const float*)d_in[19];

    float* out = (float*)d_out;
    float* ws  = (float*)d_ws;

    // Workspace (float offsets). X1 lives at [0, 28.4MF); X2 at 28.5MF+.
    // After conv1b, X1 region is reused for everything downstream.
    unsigned short* X1h = (unsigned short*)(ws);
    unsigned short* X1m = (unsigned short*)(ws + 9961472);    //  9.5 MF
    unsigned short* X1l = (unsigned short*)(ws + 19922944);   // 19.0 MF
    unsigned short* X2h = (unsigned short*)(ws + 29884416);   // 28.5 MF
    unsigned short* X2m = (unsigned short*)(ws + 30670848);   // 29.25 MF
    unsigned short* X2l = (unsigned short*)(ws + 31457280);   // 30.0 MF (ends 30.66)
    unsigned short* X3h = (unsigned short*)(ws);              //  0.0 MF
    unsigned short* X3m = (unsigned short*)(ws + 1572864);    //  1.5 MF
    unsigned short* X3l = (unsigned short*)(ws + 3145728);    //  3.0 MF
    float*  t2  = ws + 4718592;                               //  4.5 MF
    unsigned short* X4h = (unsigned short*)(ws + 7340032);    //  7.0 MF
    unsigned short* X4m = (unsigned short*)(ws + 7864320);    //  7.5 MF
    unsigned short* X4l = (unsigned short*)(ws + 8388608);    //  8.0 MF
    unsigned short* X5h = (unsigned short*)(ws + 8912896);    //  8.5 MF
    unsigned short* X5m = (unsigned short*)(ws + 9961472 + 1048576); // 10.5 MF (X1m dead zone not used before conv1b? no-- see order)
    unsigned short* X5l = (unsigned short*)(ws + 12058624);   // 11.5 MF
    float*  t5  = ws + 13107200;                              // 12.5 MF
    float*  part= ws + 14680064;                              // 14.0 MF
    float*  x1  = ws + 16777216;                              // 16.0 MF
    float*  x2  = x1 + 32768;
    float*  prep= x2 + 32768;
    int*    pts = (int*)(prep + 2048);
    // NOTE: X5m at 10.5MF = ws+11010048. (computed literal below used directly)
    X5m = (unsigned short*)(ws + 11010048);

    // Weight packing (independent of X buffers)
    pack_w1b<<<36, 256, 0, stream>>>(w1b);
    pack_wN<<<72, 256, 0, stream>>>(w2a, 64, 32, 0);
    pack_wN<<<144, 256, 0, stream>>>(w2b, 64, 64, 18432);
    pack_wN<<<288, 256, 0, stream>>>(w3a, 128, 64, 55296);
    pack_wN<<<576, 256, 0, stream>>>(w3b, 128, 128, 129024);

    // Border zeros for X1, X2 (outside the X1 region for X2)
    border_zero_p<98, 32><<<3104, 256, 0, stream>>>(X1h, X1m, X1l);
    border_zero_p<26, 32><<<800, 256, 0, stream>>>(X2h, X2m, X2l);

    // conv1a: image -> packed X1
    conv1a_pack<<<dim3(36, 64), 256, 0, stream>>>(image, w1a, b1a, X1h, X1m, X1l);
    // conv1b (MFMA) + fused 4x4 pool -> packed X2
    conv1b_mfma<<<dim3(3, 24, 64), 256, 0, stream>>>(X1h, X1m, X1l, b1b,
                                                     X2h, X2m, X2l);

    // X1 now dead; zero borders of downstream packed tensors (in X1 region)
    border_zero_p<26, 64><<<1600, 256, 0, stream>>>(X3h, X3m, X3l);
    border_zero_p<14, 64><<<832, 256, 0, stream>>>(X4h, X4m, X4l);
    border_zero_p<14, 128><<<1664, 256, 0, stream>>>(X5h, X5m, X5l);

    // conv2a: X2 -> packed X3 (64 oc).  jobs = 1152*2 -> 576 blocks
    convN_mfma<32, 24, 2, 0><<<576, 256, 0, stream>>>(
        X2h, X2m, X2l, 0, b2a, X3h, X3m, X3l, nullptr);
    // conv2b: X3 -> fp32 t2 (64,64,24,24)
    convN_mfma<64, 24, 2, 1><<<576, 256, 0, stream>>>(
        X3h, X3m, X3l, 18432, b2b, nullptr, nullptr, nullptr, t2);
    // pool2 + pack: t2 -> X4
    pool2_pack<<<2304, 256, 0, stream>>>(t2, X4h, X4m, X4l);
    // conv3a: X4 -> packed X5 (128 oc).  jobs = 288*4 -> 288 blocks
    convN_mfma<64, 12, 4, 0><<<288, 256, 0, stream>>>(
        X4h, X4m, X4l, 55296, b3a, X5h, X5m, X5l, nullptr);
    // conv3b: X5 -> fp32 t5 = x (64,128,12,12)
    convN_mfma<128, 12, 4, 1><<<288, 256, 0, stream>>>(
        X5h, X5m, X5l, 129024, b3b, nullptr, nullptr, nullptr, t5);

    // linear stack
    lin1_partial<<<dim3(8, KSPLIT), 256, 0, stream>>>(t5, wl1, part);
    lin1_reduce<<<(64 * HIDLINc + 255) / 256, 256, 0, stream>>>(part, bl1, x1);
    lin2_k<<<dim3(8, 16), 256, 0, stream>>>(x1, wl2, bl2, x2);
    lin3_k<<<6, 256, 0, stream>>>(x2, wl3, bl3, prep);
    head_k<<<2, 256, 0, stream>>>(prep, noise,
                                  out + (size_t)BB * Gc * CIc * HGc * WGc,
                                  out + (size_t)BB * Gc * CIc * HGc * WGc + BB * Gc * 2,
                                  pts);
    patch_k<<<BB * Gc, 256, 0, stream>>>(image, pts, out);
}

// Round 10
// 442.503 us; speedup vs baseline: 3.4852x; 1.0179x over previous
//
#include <hip/hip_runtime.h>
#include <math.h>

// Problem constants
constexpr int BB  = 64;
constexpr int CIc = 3;
constexpr int HIc = 96, WIc = 96;
constexpr int Gc  = 8, HGc = 16, WGc = 16;
constexpr int HIDc = 18432;
constexpr int HIDLINc = 512;

using short8 = __attribute__((ext_vector_type(8))) short;
using s4     = __attribute__((ext_vector_type(4))) short;
using f32x16 = __attribute__((ext_vector_type(16))) float;

// bf16 split helpers (RNE, used on weight/packed paths)
__device__ inline unsigned short bfr(float f) {
    unsigned int u = __float_as_uint(f);
    u = (u + 0x7FFFu + ((u >> 16) & 1u)) >> 16;
    return (unsigned short)u;
}
__device__ inline float ubf(unsigned short s) {
    return __uint_as_float(((unsigned int)s) << 16);
}

// Truncation 3-split of 8 fp32 (exact: v = h+m+l). ~9 VALU/value, hidden
// under the 6-MFMA group (192 cyc) via VALU/MFMA co-issue.
__device__ inline void split3(uint4 c0, uint4 c1, short8& H, short8& M, short8& L)
{
    unsigned int u[8] = {c0.x, c0.y, c0.z, c0.w, c1.x, c1.y, c1.z, c1.w};
#pragma unroll
    for (int j = 0; j < 8; ++j) {
        unsigned int uu = u[j];
        H[j] = (short)(uu >> 16);
        float r1 = __uint_as_float(uu) - __uint_as_float(uu & 0xFFFF0000u);
        unsigned int u1 = __float_as_uint(r1);
        M[j] = (short)(u1 >> 16);
        float r2 = r1 - __uint_as_float(u1 & 0xFFFF0000u);
        L[j] = (short)(__float_as_uint(r2) >> 16);
    }
}

// conv1b weight tables: [s=18][g=2][oc=32][j=8], k = s*16+g*8+j = tap*32+ci
__device__ __attribute__((aligned(16))) unsigned short g_wh[9216];
__device__ __attribute__((aligned(16))) unsigned short g_wm[9216];
__device__ __attribute__((aligned(16))) unsigned short g_wl[9216];

// generic conv weight tables, per chunk [s][g][oc32][j], k = tap*CIN+ci
// offsets (shorts): 2a=0, 2b=18432, 3a=55296, 3b=129024
__device__ __attribute__((aligned(16))) unsigned short g_wph[276480];
__device__ __attribute__((aligned(16))) unsigned short g_wpm[276480];
__device__ __attribute__((aligned(16))) unsigned short g_wpl[276480];

__device__ inline void packN_one(const float* __restrict__ w, int CIN, int ofs,
                                 int idx)
{
    int chsz = 288 * CIN;
    int chunk = idx / chsz;
    int t = idx - chunk * chsz;
    int s = t >> 9;
    int rr = t & 511;
    int g = rr >> 8, oc32 = (rr >> 3) & 31, j = rr & 7;
    int nc16 = CIN / 16;
    int tap = s / nc16, c16 = s % nc16;
    int ci = c16 * 16 + g * 8 + j;
    int oc = chunk * 32 + oc32;
    float v = w[((size_t)oc * CIN + ci) * 9 + tap];
    unsigned short h = bfr(v);
    float r1 = v - ubf(h);
    unsigned short m = bfr(r1);
    g_wph[ofs + idx] = h; g_wpm[ofs + idx] = m; g_wpl[ofs + idx] = bfr(r1 - ubf(m));
}

// One kernel packs all five conv weight tables.
__global__ void pack_all(const float* __restrict__ w1b, const float* __restrict__ w2a,
                         const float* __restrict__ w2b, const float* __restrict__ w3a,
                         const float* __restrict__ w3b)
{
    int idx = blockIdx.x * 256 + threadIdx.x;
    if (idx < 9216) {
        int j = idx & 7, oc = (idx >> 3) & 31, g = (idx >> 8) & 1, s = idx >> 9;
        int ci = 16 * (s & 1) + 8 * g + j;
        int tap = s >> 1;
        float v = w1b[(oc * 32 + ci) * 9 + tap];
        unsigned short h = bfr(v);
        float r1 = v - ubf(h);
        unsigned short m = bfr(r1);
        g_wh[idx] = h; g_wm[idx] = m; g_wl[idx] = bfr(r1 - ubf(m));
    } else if (idx < 27648) {
        packN_one(w2a, 32, 0, idx - 9216);
    } else if (idx < 64512) {
        packN_one(w2b, 64, 18432, idx - 27648);
    } else if (idx < 138240) {
        packN_one(w3a, 64, 55296, idx - 64512);
    } else if (idx < 285696) {
        packN_one(w3b, 128, 129024, idx - 138240);
    }
}

// Zero the 1-px border ring of padded channel-last fp32 tensor [BB][98][98][32]
__global__ void border_zero_f(float* __restrict__ X)
{
    constexpr int RING = 388, C = 32;
    constexpr int TOT = BB * RING * C;
    int idx = blockIdx.x * 256 + threadIdx.x;
    if (idx >= TOT) return;
    int ci = idx % C;
    int cell = (idx / C) % RING;
    int b = idx / (C * RING);
    int y, x;
    if (cell < 98)       { y = 0;  x = cell; }
    else if (cell < 196) { y = 97; x = cell - 98; }
    else { int t = cell - 196; y = 1 + (t >> 1); x = (t & 1) ? 97 : 0; }
    X[((size_t)(b * 98 + y) * 98 + x) * C + ci] = 0.0f;
}

// Zero border ring of packed channel-last tensors [BB][PAD][PAD][C]
template<int PAD, int C>
__global__ void border_zero_p(unsigned short* __restrict__ Xh,
                              unsigned short* __restrict__ Xm,
                              unsigned short* __restrict__ Xl)
{
    constexpr int RING = 4 * PAD - 4;
    constexpr int TOT = BB * RING * C;
    int idx = blockIdx.x * 256 + threadIdx.x;
    if (idx >= TOT) return;
    int ci = idx % C;
    int cell = (idx / C) % RING;
    int b = idx / (C * RING);
    int y, x;
    if (cell < PAD)          { y = 0;       x = cell; }
    else if (cell < 2 * PAD) { y = PAD - 1; x = cell - PAD; }
    else { int t = cell - 2 * PAD; y = 1 + (t >> 1); x = (t & 1) ? PAD - 1 : 0; }
    size_t a = ((size_t)(b * PAD + y) * PAD + x) * C + ci;
    Xh[a] = 0; Xm[a] = 0; Xl[a] = 0;
}

// ---------------------------------------------------------------------------
// conv1a_f32: fp32 direct conv (CIN=3) + bias + ReLU -> padded channel-last
// fp32 X1f [b][98][98][32] (no split -- conv1b splits on the fly).
// ---------------------------------------------------------------------------
__global__ __launch_bounds__(256)
void conv1a_f32(const float* __restrict__ in, const float* __restrict__ wgt,
                const float* __restrict__ bias, float* __restrict__ Xf)
{
    const int txi = blockIdx.x % 3, tyi = blockIdx.x / 3;
    const int ox = txi * 32, oy = tyi * 8;
    const int b = blockIdx.y;
    const int tid = threadIdx.x;
    const int px = tid & 31;
    const int py = tid >> 5;

    __shared__ float s_in[3][10][34];

    float acc[32];
#pragma unroll
    for (int oc = 0; oc < 32; ++oc) acc[oc] = 0.0f;

    {
        constexpr int TOT = 3 * 10 * 34;
        for (int idx = tid; idx < TOT; idx += 256) {
            int ci  = idx / 340;
            int rem = idx - ci * 340;
            int r = rem / 34;
            int c = rem - r * 34;
            int gy = oy + r - 1, gx = ox + c - 1;
            float v = 0.0f;
            if (gy >= 0 && gy < 96 && gx >= 0 && gx < 96)
                v = in[((size_t)(b * 3 + ci) * 96 + gy) * 96 + gx];
            s_in[ci][r][c] = v;
        }
        __syncthreads();

        for (int ci = 0; ci < 3; ++ci) {
            float v[3][3];
#pragma unroll
            for (int r = 0; r < 3; ++r)
#pragma unroll
                for (int c = 0; c < 3; ++c)
                    v[r][c] = s_in[ci][py + r][px + c];

#pragma unroll
            for (int oc = 0; oc < 32; ++oc) {
                const float* w9 = wgt + ((size_t)oc * 3 + ci) * 9;
                float a = acc[oc];
#pragma unroll
                for (int dy = 0; dy < 3; ++dy)
#pragma unroll
                    for (int dx = 0; dx < 3; ++dx)
                        a = fmaf(v[dy][dx], w9[dy * 3 + dx], a);
                acc[oc] = a;
            }
        }
    }

    size_t base = ((size_t)(b * 98 + oy + py + 1) * 98 + (ox + px + 1)) * 32;
#pragma unroll
    for (int q = 0; q < 8; ++q) {
        float4 st;
        st.x = fmaxf(acc[q * 4 + 0] + bias[q * 4 + 0], 0.0f);
        st.y = fmaxf(acc[q * 4 + 1] + bias[q * 4 + 1], 0.0f);
        st.z = fmaxf(acc[q * 4 + 2] + bias[q * 4 + 2], 0.0f);
        st.w = fmaxf(acc[q * 4 + 3] + bias[q * 4 + 3], 0.0f);
        *(float4*)(Xf + base + q * 4) = st;
    }
}

// ---------------------------------------------------------------------------
// conv1b_mfma: implicit-GEMM via mfma_32x32x16_bf16 with ON-THE-FLY truncated
// 3-split of fp32 B (32B/lane/iter instead of 48B packed) + next-iter
// prefetch. Fused 4x4 maxpool epilogue -> packed X2 [b][26][26][32].
// ---------------------------------------------------------------------------
__global__ __launch_bounds__(256)
void conv1b_mfma(const float* __restrict__ Xf, const float* __restrict__ bias,
                 unsigned short* __restrict__ X2h, unsigned short* __restrict__ X2m,
                 unsigned short* __restrict__ X2l)
{
    const int xt = blockIdx.x, yq = blockIdx.y, b = blockIdx.z;
    const int tid = threadIdx.x;
    const int wave = tid >> 6, lane = tid & 63;
    const int col = lane & 31, g = lane >> 5;
    const int y = yq * 4 + wave;
    const int x0 = xt * 32;

    __shared__ float sp[32][4][33];
    __shared__ float s_bias[32];
    if (tid < 32) s_bias[tid] = bias[tid];
    __syncthreads();

    const float* bp = Xf + ((size_t)(b * 98 + y) * 98 + (x0 + col)) * 32 + g * 8;

    f32x16 acc0 = {0,0,0,0,0,0,0,0,0,0,0,0,0,0,0,0};
    f32x16 acc1 = {0,0,0,0,0,0,0,0,0,0,0,0,0,0,0,0};

    // prefetch s=0 (tap 0 -> dy=0,dx=0, half=0 -> off 0)
    uint4 nxt0 = *(const uint4*)(bp);
    uint4 nxt1 = *(const uint4*)(bp + 4);

#pragma unroll
    for (int s = 0; s < 18; ++s) {
        uint4 cur0 = nxt0, cur1 = nxt1;
        if (s < 17) {
            const int sn = s + 1;
            const int tapn = sn >> 1;
            const int offn = ((tapn / 3) * 98 + (tapn % 3)) * 32 + (sn & 1) * 16;
            nxt0 = *(const uint4*)(bp + offn);
            nxt1 = *(const uint4*)(bp + offn + 4);
        }

        short8 bh, bm, bl;
        split3(cur0, cur1, bh, bm, bl);

        const int aidx = s * 512 + g * 256 + col * 8;
        short8 ah = *(const short8*)(g_wh + aidx);
        short8 am = *(const short8*)(g_wm + aidx);
        short8 al = *(const short8*)(g_wl + aidx);

        acc0 = __builtin_amdgcn_mfma_f32_32x32x16_bf16(ah, bh, acc0, 0, 0, 0);
        acc1 = __builtin_amdgcn_mfma_f32_32x32x16_bf16(ah, bm, acc1, 0, 0, 0);
        acc0 = __builtin_amdgcn_mfma_f32_32x32x16_bf16(am, bh, acc0, 0, 0, 0);
        acc1 = __builtin_amdgcn_mfma_f32_32x32x16_bf16(am, bm, acc1, 0, 0, 0);
        acc0 = __builtin_amdgcn_mfma_f32_32x32x16_bf16(al, bh, acc0, 0, 0, 0);
        acc1 = __builtin_amdgcn_mfma_f32_32x32x16_bf16(ah, bl, acc1, 0, 0, 0);
    }

#pragma unroll
    for (int r = 0; r < 16; ++r) {
        int ocr = (r & 3) + 8 * (r >> 2) + 4 * g;
        float v = acc0[r] + acc1[r] + s_bias[ocr];
        sp[ocr][wave][col] = fmaxf(v, 0.0f);
    }
    __syncthreads();

    {
        int oc = tid & 31, xq = tid >> 5;
        float mv = -INFINITY;
#pragma unroll
        for (int sy = 0; sy < 4; ++sy)
#pragma unroll
            for (int sx = 0; sx < 4; ++sx)
                mv = fmaxf(mv, sp[oc][sy][xq * 4 + sx]);
        unsigned short h = bfr(mv);
        float r1 = mv - ubf(h);
        unsigned short m = bfr(r1);
        size_t oa = ((size_t)(b * 26 + yq + 1) * 26 + xt * 8 + xq + 1) * 32 + oc;
        X2h[oa] = h; X2m[oa] = m; X2l[oa] = bfr(r1 - ubf(m));
    }
}

// ---------------------------------------------------------------------------
// convN_mfma: generic implicit-GEMM conv over padded channel-last packed
// input. OUTMODE 0: packed output; 1: fp32 NCHW + ReLU. (verified round 9)
// ---------------------------------------------------------------------------
template<int CIN, int HW, int NCHUNK, int OUTMODE>
__global__ __launch_bounds__(256)
void convN_mfma(const unsigned short* __restrict__ Xh,
                const unsigned short* __restrict__ Xm,
                const unsigned short* __restrict__ Xl,
                int wofs, const float* __restrict__ bias,
                unsigned short* __restrict__ Yh,
                unsigned short* __restrict__ Ym,
                unsigned short* __restrict__ Yl,
                float* __restrict__ Yf)
{
    constexpr int PAD = HW + 2;
    constexpr int NC16 = CIN / 16;
    constexpr int CHSZ = 288 * CIN;
    constexpr int COUT = NCHUNK * 32;

    const int tid = threadIdx.x;
    const int wid = blockIdx.x * 4 + (tid >> 6);
    const int lane = tid & 63;
    const int col = lane & 31, g = lane >> 5;

    const int chunk = wid % NCHUNK;
    const int wt = wid / NCHUNK;
    const int P = wt * 32 + col;
    const int b = P / (HW * HW);
    const int rem = P - b * (HW * HW);
    const int y = rem / HW, x = rem - y * HW;

    const size_t ib = ((size_t)(b * PAD + y) * PAD + x) * CIN + g * 8;
    const int wbase = wofs + chunk * CHSZ;

    f32x16 acc0 = {0,0,0,0,0,0,0,0,0,0,0,0,0,0,0,0};
    f32x16 acc1 = {0,0,0,0,0,0,0,0,0,0,0,0,0,0,0,0};

#pragma unroll
    for (int tap = 0; tap < 9; ++tap) {
        const int dy = tap / 3, dx = tap % 3;
        for (int c16 = 0; c16 < NC16; ++c16) {
            const int s = tap * NC16 + c16;
            const int aidx = wbase + s * 512 + g * 256 + col * 8;
            const size_t xo = ib + (size_t)((dy * PAD + dx) * CIN + c16 * 16);
            short8 ah = *(const short8*)(g_wph + aidx);
            short8 am = *(const short8*)(g_wpm + aidx);
            short8 al = *(const short8*)(g_wpl + aidx);
            short8 bh = *(const short8*)(Xh + xo);
            short8 bm = *(const short8*)(Xm + xo);
            short8 bl = *(const short8*)(Xl + xo);
            acc0 = __builtin_amdgcn_mfma_f32_32x32x16_bf16(ah, bh, acc0, 0, 0, 0);
            acc1 = __builtin_amdgcn_mfma_f32_32x32x16_bf16(ah, bm, acc1, 0, 0, 0);
            acc0 = __builtin_amdgcn_mfma_f32_32x32x16_bf16(am, bh, acc0, 0, 0, 0);
            acc1 = __builtin_amdgcn_mfma_f32_32x32x16_bf16(am, bm, acc1, 0, 0, 0);
            acc0 = __builtin_amdgcn_mfma_f32_32x32x16_bf16(al, bh, acc0, 0, 0, 0);
            acc1 = __builtin_amdgcn_mfma_f32_32x32x16_bf16(ah, bl, acc1, 0, 0, 0);
        }
    }

    if constexpr (OUTMODE == 0) {
        const size_t obase =
            ((size_t)(b * PAD + y + 1) * PAD + (x + 1)) * COUT + chunk * 32;
#pragma unroll
        for (int q = 0; q < 4; ++q) {
            s4 H, M, L;
#pragma unroll
            for (int i = 0; i < 4; ++i) {
                int r = q * 4 + i;
                int ocr = i + 8 * q + 4 * g;
                float v = fmaxf(acc0[r] + acc1[r] + bias[chunk * 32 + ocr], 0.0f);
                unsigned short h = bfr(v);
                float r1 = v - ubf(h);
                unsigned short m = bfr(r1);
                H[i] = (short)h; M[i] = (short)m; L[i] = (short)bfr(r1 - ubf(m));
            }
            *(s4*)(Yh + obase + 8 * q + 4 * g) = H;
            *(s4*)(Ym + obase + 8 * q + 4 * g) = M;
            *(s4*)(Yl + obase + 8 * q + 4 * g) = L;
        }
    } else {
#pragma unroll
        for (int r = 0; r < 16; ++r) {
            int ocr = chunk * 32 + (r & 3) + 8 * (r >> 2) + 4 * g;
            float v = fmaxf(acc0[r] + acc1[r] + bias[ocr], 0.0f);
            Yf[((size_t)(b * COUT + ocr) * HW + y) * HW + x] = v;
        }
    }
}

// ---------------------------------------------------------------------------
// pool2_pack: 2x2 maxpool of t2 (64,64,24,24) fp32 -> packed X4 [b][14][14][64]
// ---------------------------------------------------------------------------
__global__ __launch_bounds__(256)
void pool2_pack(const float* __restrict__ t2,
                unsigned short* __restrict__ X4h,
                unsigned short* __restrict__ X4m,
                unsigned short* __restrict__ X4l)
{
    int idx = blockIdx.x * 256 + threadIdx.x;
    constexpr int TOT = BB * 144 * 64;
    if (idx >= TOT) return;
    int oc = idx & 63;
    int p = (idx >> 6) % 144;
    int b = idx / (144 * 64);
    int y = p / 12, x = p % 12;
    const float* src = t2 + ((size_t)(b * 64 + oc) * 24 + 2 * y) * 24 + 2 * x;
    float v = fmaxf(fmaxf(src[0], src[1]), fmaxf(src[24], src[25]));
    unsigned short h = bfr(v);
    float r1 = v - ubf(h);
    unsigned short m = bfr(r1);
    size_t oa = ((size_t)(b * 14 + y + 1) * 14 + x + 1) * 64 + oc;
    X4h[oa] = h; X4m[oa] = m; X4l[oa] = bfr(r1 - ubf(m));
}

// ---------------------------------------------------------------------------
// lin1: (64, 18432) @ (18432, 512), split-K partials.
// ---------------------------------------------------------------------------
constexpr int KSPLIT = 64;
__global__ __launch_bounds__(256)
void lin1_partial(const float* __restrict__ x, const float* __restrict__ w,
                  float* __restrict__ partial)
{
    const int j  = threadIdx.x % 64;
    const int bg = threadIdx.x / 64;
    const int jBase = blockIdx.x * 64;
    const int k  = blockIdx.y;
    const int i0 = k * 288;

    __shared__ float s_x[32][64];

    float acc[16];
#pragma unroll
    for (int u = 0; u < 16; ++u) acc[u] = 0.0f;

    for (int ib = 0; ib < 288; ib += 32) {
        __syncthreads();
        {
            int lb = threadIdx.x / 4;
            int lo = (threadIdx.x % 4) * 8;
            const float* src = x + (size_t)lb * HIDc + i0 + ib + lo;
            float4 a0 = *(const float4*)(src);
            float4 a1 = *(const float4*)(src + 4);
            float tmp[8] = {a0.x, a0.y, a0.z, a0.w, a1.x, a1.y, a1.z, a1.w};
#pragma unroll
            for (int r = 0; r < 8; ++r) s_x[lo + r][lb] = tmp[r];
        }
        __syncthreads();

        for (int ii = 0; ii < 32; ++ii) {
            float wv = w[(size_t)(i0 + ib + ii) * HIDLINc + jBase + j];
            const float4* xp = (const float4*)&s_x[ii][bg * 16];
            float4 x0 = xp[0], x1 = xp[1], x2 = xp[2], x3 = xp[3];
            acc[0]  = fmaf(x0.x, wv, acc[0]);
            acc[1]  = fmaf(x0.y, wv, acc[1]);
            acc[2]  = fmaf(x0.z, wv, acc[2]);
            acc[3]  = fmaf(x0.w, wv, acc[3]);
            acc[4]  = fmaf(x1.x, wv, acc[4]);
            acc[5]  = fmaf(x1.y, wv, acc[5]);
            acc[6]  = fmaf(x1.z, wv, acc[6]);
            acc[7]  = fmaf(x1.w, wv, acc[7]);
            acc[8]  = fmaf(x2.x, wv, acc[8]);
            acc[9]  = fmaf(x2.y, wv, acc[9]);
            acc[10] = fmaf(x2.z, wv, acc[10]);
            acc[11] = fmaf(x2.w, wv, acc[11]);
            acc[12] = fmaf(x3.x, wv, acc[12]);
            acc[13] = fmaf(x3.y, wv, acc[13]);
            acc[14] = fmaf(x3.z, wv, acc[14]);
            acc[15] = fmaf(x3.w, wv, acc[15]);
        }
    }

#pragma unroll
    for (int u = 0; u < 16; ++u) {
        int b = bg * 16 + u;
        partial[((size_t)k * 64 + b) * HIDLINc + jBase + j] = acc[u];
    }
}

__global__ void lin1_reduce(const float* __restrict__ partial,
                            const float* __restrict__ bias,
                            float* __restrict__ x1)
{
    int idx = blockIdx.x * blockDim.x + threadIdx.x;
    if (idx >= 64 * HIDLINc) return;
    int j = idx % HIDLINc;
    float s = 0.0f;
    for (int k = 0; k < KSPLIT; ++k)
        s += partial[(size_t)k * 64 * HIDLINc + idx];
    x1[idx] = fmaxf(s + bias[j], 0.0f);
}

__global__ __launch_bounds__(256)
void lin2_k(const float* __restrict__ x1, const float* __restrict__ w,
            const float* __restrict__ bias, float* __restrict__ x2)
{
    const int j  = threadIdx.x % 64;
    const int bl = threadIdx.x / 64;
    const int jBase = blockIdx.x * 64;
    const int b = blockIdx.y * 4 + bl;

    __shared__ float s_x[4][HIDLINc];
    for (int idx = threadIdx.x; idx < 4 * HIDLINc; idx += 256)
        s_x[idx / HIDLINc][idx % HIDLINc] =
            x1[(size_t)(blockIdx.y * 4 + idx / HIDLINc) * HIDLINc + idx % HIDLINc];
    __syncthreads();

    float acc = 0.0f;
    for (int i = 0; i < HIDLINc; ++i)
        acc = fmaf(s_x[bl][i], w[(size_t)i * HIDLINc + jBase + j], acc);
    x2[(size_t)b * HIDLINc + jBase + j] = fmaxf(acc + bias[jBase + j], 0.0f);
}

__global__ void lin3_k(const float* __restrict__ x2, const float* __restrict__ w,
                       const float* __restrict__ bias, float* __restrict__ prep)
{
    int idx = blockIdx.x * blockDim.x + threadIdx.x;
    if (idx >= 64 * 24) return;
    int j = idx % 24, b = idx / 24;
    float acc = bias[j];
    for (int i = 0; i < HIDLINc; ++i)
        acc = fmaf(x2[(size_t)b * HIDLINc + i], w[i * 24 + j], acc);
    prep[idx] = acc;
}

__global__ void head_k(const float* __restrict__ prep, const float* __restrict__ noise,
                       float* __restrict__ outMeans, float* __restrict__ outSigmas,
                       int* __restrict__ pts)
{
    int id = blockIdx.x * blockDim.x + threadIdx.x;
    if (id >= BB * Gc) return;
    float m0 = prep[id * 3 + 0];
    float m1 = prep[id * 3 + 1];
    float sraw = prep[id * 3 + 2];
    float s = sraw + 2.0f;
    float sig = fmaxf(s, 0.0f) + log1pf(expf(-fabsf(s)));
    sig += 1e-7f;
    float sg = sig * 95.0f;
    outMeans[id * 2 + 0] = m0;
    outMeans[id * 2 + 1] = m1;
    outSigmas[id * 2 + 0] = sg;
    outSigmas[id * 2 + 1] = sg;
    float sa0 = m0 + sg * noise[id * 2 + 0];
    float sa1 = m1 + sg * noise[id * 2 + 1];
    float t0 = 1.0f / (1.0f + expf(-sa0));
    float t1 = 1.0f / (1.0f + expf(-sa1));
    pts[id * 2 + 0] = (int)rintf(t0 * 79.0f);
    pts[id * 2 + 1] = (int)rintf(t1 * 79.0f);
}

__global__ __launch_bounds__(256)
void patch_k(const float* __restrict__ image, const int* __restrict__ pts,
             float* __restrict__ outR)
{
    int id = blockIdx.x;
    int b = id / Gc;
    int p0 = pts[id * 2 + 0];
    int p1 = pts[id * 2 + 1];
    for (int idx = threadIdx.x; idx < CIc * HGc * WGc; idx += 256) {
        int c = idx / (HGc * WGc), rem = idx % (HGc * WGc);
        int hh = rem / WGc, ww = rem % WGc;
        outR[(size_t)id * (CIc * HGc * WGc) + idx] =
            image[((size_t)(b * CIc + c) * HIc + p0 + hh) * WIc + p1 + ww];
    }
}

// ---------------------------------------------------------------------------
extern "C" void kernel_launch(void* const* d_in, const int* in_sizes, int n_in,
                              void* d_out, int out_size, void* d_ws, size_t ws_size,
                              hipStream_t stream)
{
    const float* image = (const float*)d_in[0];
    const float* noise = (const float*)d_in[1];
    const float* w1a = (const float*)d_in[2];
    const float* b1a = (const float*)d_in[3];
    const float* w1b = (const float*)d_in[4];
    const float* b1b = (const float*)d_in[5];
    const float* w2a = (const float*)d_in[6];
    const float* b2a = (const float*)d_in[7];
    const float* w2b = (const float*)d_in[8];
    const float* b2b = (const float*)d_in[9];
    const float* w3a = (const float*)d_in[10];
    const float* b3a = (const float*)d_in[11];
    const float* w3b = (const float*)d_in[12];
    const float* b3b = (const float*)d_in[13];
    const float* wl1 = (const float*)d_in[14];
    const float* bl1 = (const float*)d_in[15];
    const float* wl2 = (const float*)d_in[16];
    const float* bl2 = (const float*)d_in[17];
    const float* wl3 = (const float*)d_in[18];
    const float* bl3 = (const float*)d_in[19];

    float* out = (float*)d_out;
    float* ws  = (float*)d_ws;

    // Workspace (float offsets). X1f fp32 [0, 19.67M floats); X2 at 28.5MF.
    // After conv1b, the X1f region is reused for everything downstream.
    float* X1f = ws;                                          // 19,668,992 floats
    unsigned short* X2h = (unsigned short*)(ws + 29884416);   // 28.5 MF
    unsigned short* X2m = (unsigned short*)(ws + 30670848);   // 29.25 MF
    unsigned short* X2l = (unsigned short*)(ws + 31457280);   // 30.0 MF
    unsigned short* X3h = (unsigned short*)(ws);
    unsigned short* X3m = (unsigned short*)(ws + 1572864);
    unsigned short* X3l = (unsigned short*)(ws + 3145728);
    float*  t2  = ws + 4718592;
    unsigned short* X4h = (unsigned short*)(ws + 7340032);
    unsigned short* X4m = (unsigned short*)(ws + 7864320);
    unsigned short* X4l = (unsigned short*)(ws + 8388608);
    unsigned short* X5h = (unsigned short*)(ws + 8912896);
    unsigned short* X5m = (unsigned short*)(ws + 11010048);
    unsigned short* X5l = (unsigned short*)(ws + 12058624);
    float*  t5  = ws + 13107200;
    float*  part= ws + 14680064;
    float*  x1  = ws + 16777216;
    float*  x2  = x1 + 32768;
    float*  prep= x2 + 32768;
    int*    pts = (int*)(prep + 2048);

    // All weight tables in one launch
    pack_all<<<1116, 256, 0, stream>>>(w1b, w2a, w2b, w3a, w3b);

    // Border zeros for X1f (fp32) and X2
    border_zero_f<<<3104, 256, 0, stream>>>(X1f);
    border_zero_p<26, 32><<<800, 256, 0, stream>>>(X2h, X2m, X2l);

    // conv1a: image -> fp32 channel-last X1f
    conv1a_f32<<<dim3(36, 64), 256, 0, stream>>>(image, w1a, b1a, X1f);
    // conv1b (MFMA, on-the-fly split) + fused 4x4 pool -> packed X2
    conv1b_mfma<<<dim3(3, 24, 64), 256, 0, stream>>>(X1f, b1b, X2h, X2m, X2l);

    // X1f now dead; zero borders of downstream packed tensors (in X1f region)
    border_zero_p<26, 64><<<1600, 256, 0, stream>>>(X3h, X3m, X3l);
    border_zero_p<14, 64><<<832, 256, 0, stream>>>(X4h, X4m, X4l);
    border_zero_p<14, 128><<<1664, 256, 0, stream>>>(X5h, X5m, X5l);

    // conv2a: X2 -> packed X3 (64 oc)
    convN_mfma<32, 24, 2, 0><<<576, 256, 0, stream>>>(
        X2h, X2m, X2l, 0, b2a, X3h, X3m, X3l, nullptr);
    // conv2b: X3 -> fp32 t2 (64,64,24,24)
    convN_mfma<64, 24, 2, 1><<<576, 256, 0, stream>>>(
        X3h, X3m, X3l, 18432, b2b, nullptr, nullptr, nullptr, t2);
    // pool2 + pack: t2 -> X4
    pool2_pack<<<2304, 256, 0, stream>>>(t2, X4h, X4m, X4l);
    // conv3a: X4 -> packed X5 (128 oc)
    convN_mfma<64, 12, 4, 0><<<288, 256, 0, stream>>>(
        X4h, X4m, X4l, 55296, b3a, X5h, X5m, X5l, nullptr);
    // conv3b: X5 -> fp32 t5 = x (64,128,12,12)
    convN_mfma<128, 12, 4, 1><<<288, 256, 0, stream>>>(
        X5h, X5m, X5l, 129024, b3b, nullptr, nullptr, nullptr, t5);

    // linear stack
    lin1_partial<<<dim3(8, KSPLIT), 256, 0, stream>>>(t5, wl1, part);
    lin1_reduce<<<(64 * HIDLINc + 255) / 256, 256, 0, stream>>>(part, bl1, x1);
    lin2_k<<<dim3(8, 16), 256, 0, stream>>>(x1, wl2, bl2, x2);
    lin3_k<<<6, 256, 0, stream>>>(x2, wl3, bl3, prep);
    head_k<<<2, 256, 0, stream>>>(prep, noise,
                                  out + (size_t)BB * Gc * CIc * HGc * WGc,
                                  out + (size_t)BB * Gc * CIc * HGc * WGc + BB * Gc * 2,
                                  pts);
    patch_k<<<BB * Gc, 256, 0, stream>>>(image, pts, out);
}